// Round 1
// baseline (923.707 us; speedup 1.0000x reference)
//
#include <hip/hip_runtime.h>
#include <cstdint>
#include <cstddef>

typedef unsigned int u32;
typedef unsigned long long u64;

#define NBATCH 16
#define NA 9
#define HF 160
#define WF 160
#define HWC (HF*WF)          // 25600
#define NPB (NA*HWC)         // 230400 anchors per image
#define PRE_N 6000
#define POST_N 300
#define SEL_CAP 8192
#define NBIN 2048

// Anchor constants derived exactly from generate_anchors(16,[0.5,1,2],[8,16,32]):
// all anchors have center (8,8) at cell (0,0); only w/h differ.
__constant__ float c_AW[9] = {184.f,368.f,736.f,128.f,256.f,512.f,88.f,176.f,352.f};
__constant__ float c_AH[9] = {96.f,192.f,384.f,128.f,256.f,512.f,176.f,352.f,704.f};

__device__ __forceinline__ void box_from_deltas(
    const float* __restrict__ bd, int b, int a, int pos,
    float imH, float imW, float ms,
    float& x1, float& y1, float& x2, float& y2, bool& keep)
{
  int y = pos / WF;
  int x = pos - y * WF;
  size_t base = ((size_t)(b * 4 * NA) + 4 * a) * HWC + (size_t)pos;
  float d0 = bd[base];
  float d1 = bd[base + HWC];
  float d2 = bd[base + 2 * HWC];
  float d3 = bd[base + 3 * HWC];
  float aw = c_AW[a], ah = c_AH[a];
  float acx = (float)x * 16.0f + 8.0f;
  float acy = (float)y * 16.0f + 8.0f;
  float pcx = d0 * aw + acx;
  float pcy = d1 * ah + acy;
  float pw  = expf(d2) * aw;
  float ph  = expf(d3) * ah;
  x1 = fminf(fmaxf(pcx - 0.5f * pw, 0.0f), imW - 1.0f);
  y1 = fminf(fmaxf(pcy - 0.5f * ph, 0.0f), imH - 1.0f);
  x2 = fminf(fmaxf(pcx + 0.5f * pw, 0.0f), imW - 1.0f);
  y2 = fminf(fmaxf(pcy + 0.5f * ph, 0.0f), imH - 1.0f);
  keep = ((x2 - x1 + 1.0f) >= ms) && ((y2 - y1 + 1.0f) >= ms);
}

__global__ void k_init(u32* __restrict__ hist, u64* __restrict__ prefix, u32* __restrict__ kth,
                       u32* __restrict__ done, u32* __restrict__ selcnt, u32* __restrict__ nvalid) {
  int gid = blockIdx.x * blockDim.x + threadIdx.x;
  if (gid < NBATCH * NBIN) hist[gid] = 0;
  if (gid < NBATCH) {
    prefix[gid] = 0; kth[gid] = PRE_N; done[gid] = 0; selcnt[gid] = 0; nvalid[gid] = PRE_N;
  }
}

// One thread per (b, a, pos); a-major layout so score + delta loads are coalesced.
// Key: high 32 = order-flipped score (descending), low 32 = reference flat index
// i = pos*9 + a (ascending tie-break) -> ascending u64 sort == stable top_k order.
__global__ void k_scores(const float* __restrict__ sm, const float* __restrict__ bd,
                         const float* __restrict__ info, u64* __restrict__ keys) {
  int gid = blockIdx.x * 256 + threadIdx.x;
  int b = gid / NPB;
  int t = gid - b * NPB;
  int a = t / HWC;
  int pos = t - a * HWC;
  float imH = info[b*3+0], imW = info[b*3+1], ms = 16.0f * info[b*3+2];
  float s = sm[((size_t)(b * 2 * NA) + NA + a) * HWC + (size_t)pos];
  float x1, y1, x2, y2; bool keep;
  box_from_deltas(bd, b, a, pos, imH, imW, ms, x1, y1, x2, y2, keep);
  if (!keep) s = __uint_as_float(0xFF800000u);  // -inf
  u32 su = __float_as_uint(s);
  u32 asc = (su & 0x80000000u) ? ~su : (su | 0x80000000u);
  u32 desc = ~asc;
  u32 idx = (u32)(pos * NA + a);
  keys[gid] = ((u64)desc << 32) | (u64)idx;
}

// Radix-select pass: histogram of current candidate set (keys matching prefix).
__global__ void k_hist(const u64* __restrict__ keys, const u32* __restrict__ done,
                       const u64* __restrict__ prefix_arr, u32* __restrict__ hist,
                       int first, int shift, int width) {
  int img = blockIdx.y;
  if (done[img]) return;
  __shared__ u32 lh[NBIN];
  for (int i = threadIdx.x; i < NBIN; i += 256) lh[i] = 0;
  __syncthreads();
  u64 prefix = prefix_arr[img];
  const u64* kp = keys + (size_t)img * NPB + (size_t)blockIdx.x * 3840;
  u32 dmask = (1u << width) - 1u;
  if (first) {
    for (int j = 0; j < 15; j++) {
      u64 key = kp[j * 256 + threadIdx.x];
      atomicAdd(&lh[(u32)(key >> shift) & dmask], 1u);
    }
  } else {
    int hs = shift + width;
    for (int j = 0; j < 15; j++) {
      u64 key = kp[j * 256 + threadIdx.x];
      if ((key >> hs) == prefix) atomicAdd(&lh[(u32)(key >> shift) & dmask], 1u);
    }
  }
  __syncthreads();
  u32* gh = hist + img * NBIN;
  for (int i = threadIdx.x; i < NBIN; i += 256) { u32 v = lh[i]; if (v) atomicAdd(&gh[i], v); }
}

// Pick the bin containing the k-th smallest; stop early once selecting the whole
// boundary bin keeps M = (#keys <= threshold) within SEL_CAP (always true by pass 6).
__global__ void k_select(u32* __restrict__ hist, u64* __restrict__ prefix_arr, u32* __restrict__ kth,
                         u32* __restrict__ done, u64* __restrict__ thresh, int shift, int width) {
  int img = blockIdx.x;
  if (done[img]) return;
  int tid = threadIdx.x;
  __shared__ u32 sc[256];
  u32* h = hist + img * NBIN;
  u32 loc[8];
  u32 tot = 0;
  for (int j = 0; j < 8; j++) { loc[j] = h[tid * 8 + j]; tot += loc[j]; }
  for (int j = 0; j < 8; j++) h[tid * 8 + j] = 0;  // reset for next pass
  sc[tid] = tot;
  __syncthreads();
  for (int off = 1; off < 256; off <<= 1) {
    u32 v = sc[tid];
    u32 add = (tid >= off) ? sc[tid - off] : 0u;
    __syncthreads();
    sc[tid] = v + add;
    __syncthreads();
  }
  u32 incl = sc[tid];
  u32 excl = incl - tot;
  u32 k = kth[img];
  if (k > excl && k <= incl) {
    u32 run = excl;
    for (int j = 0; j < 8; j++) {
      run += loc[j];
      if (run >= k) {
        u32 bin = (u32)(tid * 8 + j);
        u32 below = run - loc[j];
        u32 cnt = loc[j];
        u32 knew = k - below;
        u64 pfull = (prefix_arr[img] << width) | (u64)bin;
        u32 M = (u32)PRE_N - knew + cnt;   // #keys <= (pfull|ones) globally
        if (M <= SEL_CAP) {
          done[img] = 1;
          u64 lowmask = (shift > 0) ? ((1ULL << shift) - 1ULL) : 0ULL;
          thresh[img] = (pfull << shift) | lowmask;
        } else {
          prefix_arr[img] = pfull;
          kth[img] = knew;
        }
        break;
      }
    }
  }
}

__global__ void k_compact(const u64* __restrict__ keys, const u64* __restrict__ thresh,
                          u32* __restrict__ selcnt, u64* __restrict__ sel) {
  int img = blockIdx.y;
  u64 T = thresh[img];
  const u64* kp = keys + (size_t)img * NPB + (size_t)blockIdx.x * 3840;
  int lane = threadIdx.x & 63;
  u64* sp = sel + (size_t)img * SEL_CAP;
  for (int j = 0; j < 15; j++) {
    u64 key = kp[j * 256 + threadIdx.x];
    bool pick = (key <= T);
    u64 mask = __ballot(pick);
    if (mask) {
      u32 cnt = (u32)__popcll(mask);
      int leader = __ffsll((long long)mask) - 1;
      u32 base = 0;
      if (lane == leader) base = atomicAdd(&selcnt[img], cnt);
      base = __shfl(base, leader);
      if (pick) {
        u32 off = (u32)__popcll(mask & ((1ULL << lane) - 1ULL));
        u32 p = base + off;
        if (p < SEL_CAP) sp[p] = key;
      }
    }
  }
}

// Full bitonic sort of <=8192 keys in LDS; first 6000 are the exact stable top-k.
__global__ void __launch_bounds__(1024) k_sort(const u64* __restrict__ sel, const u32* __restrict__ selcnt,
                                               u32* __restrict__ sidx, u32* __restrict__ nvalid) {
  __shared__ u64 s[SEL_CAP];   // 64 KiB
  int img = blockIdx.x;
  int tid = threadIdx.x;
  u32 cnt = selcnt[img];
  if (cnt > SEL_CAP) cnt = SEL_CAP;
  const u64* sp = sel + (size_t)img * SEL_CAP;
  for (int i = tid; i < SEL_CAP; i += 1024) s[i] = (i < (int)cnt) ? sp[i] : ~0ULL;
  __syncthreads();
  for (int k = 2; k <= SEL_CAP; k <<= 1) {
    for (int j = k >> 1; j > 0; j >>= 1) {
      for (int i = tid; i < SEL_CAP; i += 1024) {
        int p = i ^ j;
        if (p > i) {
          u64 a = s[i], b = s[p];
          bool up = ((i & k) == 0);
          if (up ? (a > b) : (a < b)) { s[i] = b; s[p] = a; }
        }
      }
      __syncthreads();
    }
  }
  for (int r = tid; r < PRE_N; r += 1024) {
    u64 key = s[r];
    u32 hi = (u32)(key >> 32);
    bool valid = hi < 0xFF800000u;              // score > -inf
    sidx[img * PRE_N + r] = valid ? (u32)key : 0xFFFFFFFFu;
    bool pv = (r == 0) ? true : (((u32)(s[r - 1] >> 32)) < 0xFF800000u);
    if (!valid && pv) nvalid[img] = (u32)r;     // first invalid rank
  }
}

__global__ void k_gather(const float* __restrict__ bd, const float* __restrict__ info,
                         const u32* __restrict__ sidx, float4* __restrict__ boxes) {
  int gid = blockIdx.x * 256 + threadIdx.x;
  if (gid >= NBATCH * PRE_N) return;
  int img = gid / PRE_N;
  u32 iv = sidx[gid];
  float4 bx = make_float4(0.f, 0.f, 0.f, 0.f);
  if (iv != 0xFFFFFFFFu) {
    int i = (int)iv;
    int a = i % NA;
    int pos = i / NA;
    float imH = info[img*3+0], imW = info[img*3+1], ms = 16.0f * info[img*3+2];
    float x1, y1, x2, y2; bool keep;
    box_from_deltas(bd, img, a, pos, imH, imW, ms, x1, y1, x2, y2, keep);
    bx = make_float4(x1, y1, x2, y2);
  }
  boxes[gid] = bx;
}

// Lazy batched greedy NMS: batch of 64 candidates tested vs kept list (split over
// 4 waves), then wave-0 serial pass resolves within-batch dependencies via ballot.
__global__ void __launch_bounds__(256) k_nms(const float4* __restrict__ boxes,
                                             const u32* __restrict__ nvalid_arr,
                                             float* __restrict__ out) {
  int img = blockIdx.x;
  __shared__ float kx1[POST_N], ky1[POST_N], kx2[POST_N], ky2[POST_N], ka[POST_N];
  __shared__ float cx1[64], cy1[64], cx2[64], cy2[64], ca[64];
  __shared__ u64 supw[4];
  __shared__ int sh_nkept;
  int tid = threadIdx.x;
  int lane = tid & 63;
  int wv = tid >> 6;
  int nvalid = (int)nvalid_arr[img];
  if (nvalid > PRE_N) nvalid = PRE_N;
  if (tid == 0) sh_nkept = 0;
  __syncthreads();
  const float4* bb = boxes + (size_t)img * PRE_N;
  for (int base = 0; base < nvalid; base += 64) {
    if (sh_nkept >= POST_N) break;
    int bn = nvalid - base; if (bn > 64) bn = 64;
    if (tid < bn) {
      float4 c = bb[base + tid];
      cx1[tid] = c.x; cy1[tid] = c.y; cx2[tid] = c.z; cy2[tid] = c.w;
      ca[tid] = (c.z - c.x + 1.0f) * (c.w - c.y + 1.0f);
    }
    __syncthreads();
    int nk = sh_nkept;
    bool sup;
    if (lane < bn) {
      sup = false;
      float X1 = cx1[lane], Y1 = cy1[lane], X2 = cx2[lane], Y2 = cy2[lane], A0 = ca[lane];
      for (int j = wv; j < nk; j += 4) {
        float xx1 = fmaxf(kx1[j], X1);
        float yy1 = fmaxf(ky1[j], Y1);
        float xx2 = fminf(kx2[j], X2);
        float yy2 = fminf(ky2[j], Y2);
        float iw = fmaxf(0.0f, xx2 - xx1 + 1.0f);
        float ih = fmaxf(0.0f, yy2 - yy1 + 1.0f);
        float inter = iw * ih;
        float iou = inter / ((ka[j] + A0) - inter);   // same operand order as reference
        if (iou > 0.7f) { sup = true; break; }
      }
    } else {
      sup = true;
    }
    u64 m = __ballot(sup);
    if (lane == 0) supw[wv] = m;
    __syncthreads();
    if (wv == 0) {
      u64 live = ~(supw[0] | supw[1] | supw[2] | supw[3]);
      int nkept = sh_nkept;
      while (live && nkept < POST_N) {
        int c = __ffsll((long long)live) - 1;
        live &= live - 1ULL;
        float X1 = cx1[c], Y1 = cy1[c], X2 = cx2[c], Y2 = cy2[c], A0 = ca[c];
        if (lane == 0) {
          kx1[nkept] = X1; ky1[nkept] = Y1; kx2[nkept] = X2; ky2[nkept] = Y2; ka[nkept] = A0;
          float* o = out + ((size_t)img * POST_N + nkept) * 5;
          o[0] = (float)img; o[1] = X1; o[2] = Y1; o[3] = X2; o[4] = Y2;
        }
        nkept++;
        bool s2 = false;
        if ((live >> lane) & 1ULL) {
          float xx1 = fmaxf(X1, cx1[lane]);
          float yy1 = fmaxf(Y1, cy1[lane]);
          float xx2 = fminf(X2, cx2[lane]);
          float yy2 = fminf(Y2, cy2[lane]);
          float iw = fmaxf(0.0f, xx2 - xx1 + 1.0f);
          float ih = fmaxf(0.0f, yy2 - yy1 + 1.0f);
          float inter = iw * ih;
          float iou = inter / ((A0 + ca[lane]) - inter);
          s2 = iou > 0.7f;
        }
        live &= ~__ballot(s2);
      }
      if (lane == 0) sh_nkept = nkept;
    }
    __syncthreads();
  }
  int fk = sh_nkept;
  for (int r = fk + tid; r < POST_N; r += 256) {
    float* o = out + ((size_t)img * POST_N + r) * 5;
    o[0] = (float)img; o[1] = 0.f; o[2] = 0.f; o[3] = 0.f; o[4] = 0.f;
  }
}

extern "C" void kernel_launch(void* const* d_in, const int* in_sizes, int n_in,
                              void* d_out, int out_size, void* d_ws, size_t ws_size,
                              hipStream_t stream) {
  const float* sm   = (const float*)d_in[0];
  const float* bd   = (const float*)d_in[1];
  const float* info = (const float*)d_in[2];
  float* out = (float*)d_out;
  char* ws = (char*)d_ws;

  size_t off = 0;
  auto alloc = [&](size_t bytes) { size_t o = off; off += (bytes + 255) & ~(size_t)255; return o; };
  u64* keys     = (u64*)(ws + alloc((size_t)NBATCH * NPB * 8));       // ~29.5 MB
  u32* hist     = (u32*)(ws + alloc((size_t)NBATCH * NBIN * 4));
  u64* prefix   = (u64*)(ws + alloc(NBATCH * 8));
  u32* kth      = (u32*)(ws + alloc(NBATCH * 4));
  u32* done     = (u32*)(ws + alloc(NBATCH * 4));
  u32* selcnt   = (u32*)(ws + alloc(NBATCH * 4));
  u32* nvalid   = (u32*)(ws + alloc(NBATCH * 4));
  u64* thresh   = (u64*)(ws + alloc(NBATCH * 8));
  u64* sel      = (u64*)(ws + alloc((size_t)NBATCH * SEL_CAP * 8));
  u32* sidx     = (u32*)(ws + alloc((size_t)NBATCH * PRE_N * 4));
  float4* boxes = (float4*)(ws + alloc((size_t)NBATCH * PRE_N * 16));
  (void)ws_size; (void)in_sizes; (void)n_in; (void)out_size;

  hipLaunchKernelGGL(k_init, dim3(128), dim3(256), 0, stream, hist, prefix, kth, done, selcnt, nvalid);
  hipLaunchKernelGGL(k_scores, dim3(14400), dim3(256), 0, stream, sm, bd, info, keys);
  const int shifts[6] = {53, 42, 31, 20, 9, 0};
  const int widths[6] = {11, 11, 11, 11, 11, 9};
  for (int p = 0; p < 6; p++) {
    hipLaunchKernelGGL(k_hist, dim3(60, 16), dim3(256), 0, stream,
                       keys, done, prefix, hist, (p == 0) ? 1 : 0, shifts[p], widths[p]);
    hipLaunchKernelGGL(k_select, dim3(16), dim3(256), 0, stream,
                       hist, prefix, kth, done, thresh, shifts[p], widths[p]);
  }
  hipLaunchKernelGGL(k_compact, dim3(60, 16), dim3(256), 0, stream, keys, thresh, selcnt, sel);
  hipLaunchKernelGGL(k_sort, dim3(16), dim3(1024), 0, stream, sel, selcnt, sidx, nvalid);
  hipLaunchKernelGGL(k_gather, dim3(375), dim3(256), 0, stream, bd, info, sidx, boxes);
  hipLaunchKernelGGL(k_nms, dim3(16), dim3(256), 0, stream, boxes, nvalid, out);
}

// Round 2
// 403.818 us; speedup vs baseline: 2.2874x; 2.2874x over previous
//
#include <hip/hip_runtime.h>
#include <cstdint>
#include <cstddef>

typedef unsigned int u32;
typedef unsigned long long u64;

#define NBATCH 16
#define NA 9
#define HF 160
#define WF 160
#define HWC (HF*WF)          // 25600
#define NPB (NA*HWC)         // 230400 anchors per image
#define PRE_N 6000
#define POST_N 300
#define SEL_CAP 8192
#define NBIN 2048

// Anchor constants derived exactly from generate_anchors(16,[0.5,1,2],[8,16,32]):
// all anchors have center (8,8) at cell (0,0); only w/h differ.
__constant__ float c_AW[9] = {184.f,368.f,736.f,128.f,256.f,512.f,88.f,176.f,352.f};
__constant__ float c_AH[9] = {96.f,192.f,384.f,128.f,256.f,512.f,176.f,352.f,704.f};

__device__ __forceinline__ void box_from_deltas(
    const float* __restrict__ bd, int b, int a, int pos,
    float imH, float imW, float ms,
    float& x1, float& y1, float& x2, float& y2, bool& keep)
{
  int y = pos / WF;
  int x = pos - y * WF;
  size_t base = ((size_t)(b * 4 * NA) + 4 * a) * HWC + (size_t)pos;
  float d0 = bd[base];
  float d1 = bd[base + HWC];
  float d2 = bd[base + 2 * HWC];
  float d3 = bd[base + 3 * HWC];
  float aw = c_AW[a], ah = c_AH[a];
  float acx = (float)x * 16.0f + 8.0f;
  float acy = (float)y * 16.0f + 8.0f;
  float pcx = d0 * aw + acx;
  float pcy = d1 * ah + acy;
  float pw  = expf(d2) * aw;
  float ph  = expf(d3) * ah;
  x1 = fminf(fmaxf(pcx - 0.5f * pw, 0.0f), imW - 1.0f);
  y1 = fminf(fmaxf(pcy - 0.5f * ph, 0.0f), imH - 1.0f);
  x2 = fminf(fmaxf(pcx + 0.5f * pw, 0.0f), imW - 1.0f);
  y2 = fminf(fmaxf(pcy + 0.5f * ph, 0.0f), imH - 1.0f);
  keep = ((x2 - x1 + 1.0f) >= ms) && ((y2 - y1 + 1.0f) >= ms);
}

__global__ void k_init(u32* __restrict__ hist, u64* __restrict__ prefix, u32* __restrict__ kth,
                       u32* __restrict__ done, u32* __restrict__ selcnt, u32* __restrict__ nvalid) {
  int gid = blockIdx.x * blockDim.x + threadIdx.x;
  if (gid < NBATCH * NBIN) hist[gid] = 0;
  if (gid < NBATCH) {
    prefix[gid] = 0; kth[gid] = PRE_N; done[gid] = 0; selcnt[gid] = 0; nvalid[gid] = PRE_N;
  }
}

// One thread per (b, a, pos); a-major layout so score + delta loads are coalesced.
// Key: high 32 = order-flipped score (descending), low 32 = reference flat index
// i = pos*9 + a (ascending tie-break) -> ascending u64 sort == stable top_k order.
__global__ void k_scores(const float* __restrict__ sm, const float* __restrict__ bd,
                         const float* __restrict__ info, u64* __restrict__ keys) {
  int gid = blockIdx.x * 256 + threadIdx.x;
  int b = gid / NPB;
  int t = gid - b * NPB;
  int a = t / HWC;
  int pos = t - a * HWC;
  float imH = info[b*3+0], imW = info[b*3+1], ms = 16.0f * info[b*3+2];
  float s = sm[((size_t)(b * 2 * NA) + NA + a) * HWC + (size_t)pos];
  float x1, y1, x2, y2; bool keep;
  box_from_deltas(bd, b, a, pos, imH, imW, ms, x1, y1, x2, y2, keep);
  if (!keep) s = __uint_as_float(0xFF800000u);  // -inf
  u32 su = __float_as_uint(s);
  u32 asc = (su & 0x80000000u) ? ~su : (su | 0x80000000u);
  u32 desc = ~asc;
  u32 idx = (u32)(pos * NA + a);
  keys[gid] = ((u64)desc << 32) | (u64)idx;
}

// Radix-select pass: histogram of current candidate set (keys matching prefix).
__global__ void k_hist(const u64* __restrict__ keys, const u32* __restrict__ done,
                       const u64* __restrict__ prefix_arr, u32* __restrict__ hist,
                       int first, int shift, int width) {
  int img = blockIdx.y;
  if (done[img]) return;
  __shared__ u32 lh[NBIN];
  for (int i = threadIdx.x; i < NBIN; i += 256) lh[i] = 0;
  __syncthreads();
  u64 prefix = prefix_arr[img];
  const u64* kp = keys + (size_t)img * NPB + (size_t)blockIdx.x * 3840;
  u32 dmask = (1u << width) - 1u;
  if (first) {
    for (int j = 0; j < 15; j++) {
      u64 key = kp[j * 256 + threadIdx.x];
      atomicAdd(&lh[(u32)(key >> shift) & dmask], 1u);
    }
  } else {
    int hs = shift + width;
    for (int j = 0; j < 15; j++) {
      u64 key = kp[j * 256 + threadIdx.x];
      if ((key >> hs) == prefix) atomicAdd(&lh[(u32)(key >> shift) & dmask], 1u);
    }
  }
  __syncthreads();
  u32* gh = hist + img * NBIN;
  for (int i = threadIdx.x; i < NBIN; i += 256) { u32 v = lh[i]; if (v) atomicAdd(&gh[i], v); }
}

// Pick the bin containing the k-th smallest; stop early once selecting the whole
// boundary bin keeps M = (#keys <= threshold) within SEL_CAP (always true by pass 6).
__global__ void k_select(u32* __restrict__ hist, u64* __restrict__ prefix_arr, u32* __restrict__ kth,
                         u32* __restrict__ done, u64* __restrict__ thresh, int shift, int width) {
  int img = blockIdx.x;
  if (done[img]) return;
  int tid = threadIdx.x;
  __shared__ u32 sc[256];
  u32* h = hist + img * NBIN;
  u32 loc[8];
  u32 tot = 0;
  for (int j = 0; j < 8; j++) { loc[j] = h[tid * 8 + j]; tot += loc[j]; }
  for (int j = 0; j < 8; j++) h[tid * 8 + j] = 0;  // reset for next pass
  sc[tid] = tot;
  __syncthreads();
  for (int off = 1; off < 256; off <<= 1) {
    u32 v = sc[tid];
    u32 add = (tid >= off) ? sc[tid - off] : 0u;
    __syncthreads();
    sc[tid] = v + add;
    __syncthreads();
  }
  u32 incl = sc[tid];
  u32 excl = incl - tot;
  u32 k = kth[img];
  if (k > excl && k <= incl) {
    u32 run = excl;
    for (int j = 0; j < 8; j++) {
      run += loc[j];
      if (run >= k) {
        u32 bin = (u32)(tid * 8 + j);
        u32 below = run - loc[j];
        u32 cnt = loc[j];
        u32 knew = k - below;
        u64 pfull = (prefix_arr[img] << width) | (u64)bin;
        u32 M = (u32)PRE_N - knew + cnt;   // #keys <= (pfull|ones) globally
        if (M <= SEL_CAP) {
          done[img] = 1;
          u64 lowmask = (shift > 0) ? ((1ULL << shift) - 1ULL) : 0ULL;
          thresh[img] = (pfull << shift) | lowmask;
        } else {
          prefix_arr[img] = pfull;
          kth[img] = knew;
        }
        break;
      }
    }
  }
}

// Block-aggregated compaction: one global atomicAdd per BLOCK (was: per wave per
// iteration -> 3600-deep serialization on 16 hot addresses, 536 us). Threads
// count picks, LDS-scan for intra-block offsets, leader reserves a range, then
// each thread re-reads its (L1/L2-hot) keys and writes picks at its offset.
// Within-image order is arbitrary; k_sort establishes exact order afterwards.
__global__ void k_compact(const u64* __restrict__ keys, const u64* __restrict__ thresh,
                          u32* __restrict__ selcnt, u64* __restrict__ sel) {
  int img = blockIdx.y;
  int tid = threadIdx.x;
  u64 T = thresh[img];
  const u64* kp = keys + (size_t)img * NPB + (size_t)blockIdx.x * 3840;
  u32 mycnt = 0;
  #pragma unroll
  for (int j = 0; j < 15; j++) {
    u64 key = kp[j * 256 + tid];
    if (key <= T) mycnt++;
  }
  __shared__ u32 sc[256];
  __shared__ u32 sbase;
  sc[tid] = mycnt;
  __syncthreads();
  for (int off = 1; off < 256; off <<= 1) {
    u32 v = sc[tid];
    u32 add = (tid >= off) ? sc[tid - off] : 0u;
    __syncthreads();
    sc[tid] = v + add;
    __syncthreads();
  }
  if (tid == 255 && sc[255] > 0) sbase = atomicAdd(&selcnt[img], sc[255]);
  __syncthreads();
  if (mycnt == 0) return;
  u32 myoff = sbase + sc[tid] - mycnt;
  u64* sp = sel + (size_t)img * SEL_CAP;
  u32 c = 0;
  #pragma unroll
  for (int j = 0; j < 15; j++) {
    u64 key = kp[j * 256 + tid];
    if (key <= T) {
      u32 p = myoff + c;
      if (p < SEL_CAP) sp[p] = key;
      c++;
    }
  }
}

// Full bitonic sort of <=8192 keys in LDS; first 6000 are the exact stable top-k.
__global__ void __launch_bounds__(1024) k_sort(const u64* __restrict__ sel, const u32* __restrict__ selcnt,
                                               u32* __restrict__ sidx, u32* __restrict__ nvalid) {
  __shared__ u64 s[SEL_CAP];   // 64 KiB
  int img = blockIdx.x;
  int tid = threadIdx.x;
  u32 cnt = selcnt[img];
  if (cnt > SEL_CAP) cnt = SEL_CAP;
  const u64* sp = sel + (size_t)img * SEL_CAP;
  for (int i = tid; i < SEL_CAP; i += 1024) s[i] = (i < (int)cnt) ? sp[i] : ~0ULL;
  __syncthreads();
  for (int k = 2; k <= SEL_CAP; k <<= 1) {
    for (int j = k >> 1; j > 0; j >>= 1) {
      for (int i = tid; i < SEL_CAP; i += 1024) {
        int p = i ^ j;
        if (p > i) {
          u64 a = s[i], b = s[p];
          bool up = ((i & k) == 0);
          if (up ? (a > b) : (a < b)) { s[i] = b; s[p] = a; }
        }
      }
      __syncthreads();
    }
  }
  for (int r = tid; r < PRE_N; r += 1024) {
    u64 key = s[r];
    u32 hi = (u32)(key >> 32);
    bool valid = hi < 0xFF800000u;              // score > -inf
    sidx[img * PRE_N + r] = valid ? (u32)key : 0xFFFFFFFFu;
    bool pv = (r == 0) ? true : (((u32)(s[r - 1] >> 32)) < 0xFF800000u);
    if (!valid && pv) nvalid[img] = (u32)r;     // first invalid rank
  }
}

__global__ void k_gather(const float* __restrict__ bd, const float* __restrict__ info,
                         const u32* __restrict__ sidx, float4* __restrict__ boxes) {
  int gid = blockIdx.x * 256 + threadIdx.x;
  if (gid >= NBATCH * PRE_N) return;
  int img = gid / PRE_N;
  u32 iv = sidx[gid];
  float4 bx = make_float4(0.f, 0.f, 0.f, 0.f);
  if (iv != 0xFFFFFFFFu) {
    int i = (int)iv;
    int a = i % NA;
    int pos = i / NA;
    float imH = info[img*3+0], imW = info[img*3+1], ms = 16.0f * info[img*3+2];
    float x1, y1, x2, y2; bool keep;
    box_from_deltas(bd, img, a, pos, imH, imW, ms, x1, y1, x2, y2, keep);
    bx = make_float4(x1, y1, x2, y2);
  }
  boxes[gid] = bx;
}

// Lazy batched greedy NMS: batch of 64 candidates tested vs kept list (split over
// 4 waves), then wave-0 serial pass resolves within-batch dependencies via ballot.
__global__ void __launch_bounds__(256) k_nms(const float4* __restrict__ boxes,
                                             const u32* __restrict__ nvalid_arr,
                                             float* __restrict__ out) {
  int img = blockIdx.x;
  __shared__ float kx1[POST_N], ky1[POST_N], kx2[POST_N], ky2[POST_N], ka[POST_N];
  __shared__ float cx1[64], cy1[64], cx2[64], cy2[64], ca[64];
  __shared__ u64 supw[4];
  __shared__ int sh_nkept;
  int tid = threadIdx.x;
  int lane = tid & 63;
  int wv = tid >> 6;
  int nvalid = (int)nvalid_arr[img];
  if (nvalid > PRE_N) nvalid = PRE_N;
  if (tid == 0) sh_nkept = 0;
  __syncthreads();
  const float4* bb = boxes + (size_t)img * PRE_N;
  for (int base = 0; base < nvalid; base += 64) {
    if (sh_nkept >= POST_N) break;
    int bn = nvalid - base; if (bn > 64) bn = 64;
    if (tid < bn) {
      float4 c = bb[base + tid];
      cx1[tid] = c.x; cy1[tid] = c.y; cx2[tid] = c.z; cy2[tid] = c.w;
      ca[tid] = (c.z - c.x + 1.0f) * (c.w - c.y + 1.0f);
    }
    __syncthreads();
    int nk = sh_nkept;
    bool sup;
    if (lane < bn) {
      sup = false;
      float X1 = cx1[lane], Y1 = cy1[lane], X2 = cx2[lane], Y2 = cy2[lane], A0 = ca[lane];
      for (int j = wv; j < nk; j += 4) {
        float xx1 = fmaxf(kx1[j], X1);
        float yy1 = fmaxf(ky1[j], Y1);
        float xx2 = fminf(kx2[j], X2);
        float yy2 = fminf(ky2[j], Y2);
        float iw = fmaxf(0.0f, xx2 - xx1 + 1.0f);
        float ih = fmaxf(0.0f, yy2 - yy1 + 1.0f);
        float inter = iw * ih;
        float iou = inter / ((ka[j] + A0) - inter);   // same operand order as reference
        if (iou > 0.7f) { sup = true; break; }
      }
    } else {
      sup = true;
    }
    u64 m = __ballot(sup);
    if (lane == 0) supw[wv] = m;
    __syncthreads();
    if (wv == 0) {
      u64 live = ~(supw[0] | supw[1] | supw[2] | supw[3]);
      int nkept = sh_nkept;
      while (live && nkept < POST_N) {
        int c = __ffsll((long long)live) - 1;
        live &= live - 1ULL;
        float X1 = cx1[c], Y1 = cy1[c], X2 = cx2[c], Y2 = cy2[c], A0 = ca[c];
        if (lane == 0) {
          kx1[nkept] = X1; ky1[nkept] = Y1; kx2[nkept] = X2; ky2[nkept] = Y2; ka[nkept] = A0;
          float* o = out + ((size_t)img * POST_N + nkept) * 5;
          o[0] = (float)img; o[1] = X1; o[2] = Y1; o[3] = X2; o[4] = Y2;
        }
        nkept++;
        bool s2 = false;
        if ((live >> lane) & 1ULL) {
          float xx1 = fmaxf(X1, cx1[lane]);
          float yy1 = fmaxf(Y1, cy1[lane]);
          float xx2 = fminf(X2, cx2[lane]);
          float yy2 = fminf(Y2, cy2[lane]);
          float iw = fmaxf(0.0f, xx2 - xx1 + 1.0f);
          float ih = fmaxf(0.0f, yy2 - yy1 + 1.0f);
          float inter = iw * ih;
          float iou = inter / ((A0 + ca[lane]) - inter);
          s2 = iou > 0.7f;
        }
        live &= ~__ballot(s2);
      }
      if (lane == 0) sh_nkept = nkept;
    }
    __syncthreads();
  }
  int fk = sh_nkept;
  for (int r = fk + tid; r < POST_N; r += 256) {
    float* o = out + ((size_t)img * POST_N + r) * 5;
    o[0] = (float)img; o[1] = 0.f; o[2] = 0.f; o[3] = 0.f; o[4] = 0.f;
  }
}

extern "C" void kernel_launch(void* const* d_in, const int* in_sizes, int n_in,
                              void* d_out, int out_size, void* d_ws, size_t ws_size,
                              hipStream_t stream) {
  const float* sm   = (const float*)d_in[0];
  const float* bd   = (const float*)d_in[1];
  const float* info = (const float*)d_in[2];
  float* out = (float*)d_out;
  char* ws = (char*)d_ws;

  size_t off = 0;
  auto alloc = [&](size_t bytes) { size_t o = off; off += (bytes + 255) & ~(size_t)255; return o; };
  u64* keys     = (u64*)(ws + alloc((size_t)NBATCH * NPB * 8));       // ~29.5 MB
  u32* hist     = (u32*)(ws + alloc((size_t)NBATCH * NBIN * 4));
  u64* prefix   = (u64*)(ws + alloc(NBATCH * 8));
  u32* kth      = (u32*)(ws + alloc(NBATCH * 4));
  u32* done     = (u32*)(ws + alloc(NBATCH * 4));
  u32* selcnt   = (u32*)(ws + alloc(NBATCH * 4));
  u32* nvalid   = (u32*)(ws + alloc(NBATCH * 4));
  u64* thresh   = (u64*)(ws + alloc(NBATCH * 8));
  u64* sel      = (u64*)(ws + alloc((size_t)NBATCH * SEL_CAP * 8));
  u32* sidx     = (u32*)(ws + alloc((size_t)NBATCH * PRE_N * 4));
  float4* boxes = (float4*)(ws + alloc((size_t)NBATCH * PRE_N * 16));
  (void)ws_size; (void)in_sizes; (void)n_in; (void)out_size;

  hipLaunchKernelGGL(k_init, dim3(128), dim3(256), 0, stream, hist, prefix, kth, done, selcnt, nvalid);
  hipLaunchKernelGGL(k_scores, dim3(14400), dim3(256), 0, stream, sm, bd, info, keys);
  const int shifts[6] = {53, 42, 31, 20, 9, 0};
  const int widths[6] = {11, 11, 11, 11, 11, 9};
  for (int p = 0; p < 6; p++) {
    hipLaunchKernelGGL(k_hist, dim3(60, 16), dim3(256), 0, stream,
                       keys, done, prefix, hist, (p == 0) ? 1 : 0, shifts[p], widths[p]);
    hipLaunchKernelGGL(k_select, dim3(16), dim3(256), 0, stream,
                       hist, prefix, kth, done, thresh, shifts[p], widths[p]);
  }
  hipLaunchKernelGGL(k_compact, dim3(60, 16), dim3(256), 0, stream, keys, thresh, selcnt, sel);
  hipLaunchKernelGGL(k_sort, dim3(16), dim3(1024), 0, stream, sel, selcnt, sidx, nvalid);
  hipLaunchKernelGGL(k_gather, dim3(375), dim3(256), 0, stream, bd, info, sidx, boxes);
  hipLaunchKernelGGL(k_nms, dim3(16), dim3(256), 0, stream, boxes, nvalid, out);
}

// Round 3
// 322.833 us; speedup vs baseline: 2.8613x; 1.2509x over previous
//
#include <hip/hip_runtime.h>
#include <cstdint>
#include <cstddef>

typedef unsigned int u32;
typedef unsigned long long u64;

#define NBATCH 16
#define NA 9
#define HF 160
#define WF 160
#define HWC (HF*WF)          // 25600
#define NPB (NA*HWC)         // 230400 anchors per image
#define PRE_N 6000
#define POST_N 300
#define SEL_CAP 8192
#define NBIN 2048

// Anchor constants derived exactly from generate_anchors(16,[0.5,1,2],[8,16,32]):
// all anchors have center (8,8) at cell (0,0); only w/h differ.
__constant__ float c_AW[9] = {184.f,368.f,736.f,128.f,256.f,512.f,88.f,176.f,352.f};
__constant__ float c_AH[9] = {96.f,192.f,384.f,128.f,256.f,512.f,176.f,352.f,704.f};

__device__ __forceinline__ void box_from_deltas(
    const float* __restrict__ bd, int b, int a, int pos,
    float imH, float imW, float ms,
    float& x1, float& y1, float& x2, float& y2, bool& keep)
{
  int y = pos / WF;
  int x = pos - y * WF;
  size_t base = ((size_t)(b * 4 * NA) + 4 * a) * HWC + (size_t)pos;
  float d0 = bd[base];
  float d1 = bd[base + HWC];
  float d2 = bd[base + 2 * HWC];
  float d3 = bd[base + 3 * HWC];
  float aw = c_AW[a], ah = c_AH[a];
  float acx = (float)x * 16.0f + 8.0f;
  float acy = (float)y * 16.0f + 8.0f;
  float pcx = d0 * aw + acx;
  float pcy = d1 * ah + acy;
  float pw  = expf(d2) * aw;
  float ph  = expf(d3) * ah;
  x1 = fminf(fmaxf(pcx - 0.5f * pw, 0.0f), imW - 1.0f);
  y1 = fminf(fmaxf(pcy - 0.5f * ph, 0.0f), imH - 1.0f);
  x2 = fminf(fmaxf(pcx + 0.5f * pw, 0.0f), imW - 1.0f);
  y2 = fminf(fmaxf(pcy + 0.5f * ph, 0.0f), imH - 1.0f);
  keep = ((x2 - x1 + 1.0f) >= ms) && ((y2 - y1 + 1.0f) >= ms);
}

__global__ void k_init(u32* __restrict__ hist, u64* __restrict__ prefix, u32* __restrict__ kth,
                       u32* __restrict__ done, u32* __restrict__ selcnt, u32* __restrict__ nvalid) {
  int gid = blockIdx.x * blockDim.x + threadIdx.x;
  if (gid < NBATCH * NBIN) hist[gid] = 0;
  if (gid < NBATCH) {
    prefix[gid] = 0; kth[gid] = PRE_N; done[gid] = 0; selcnt[gid] = 0; nvalid[gid] = PRE_N;
  }
}

// One thread per (b, a, pos); a-major layout so score + delta loads are coalesced.
// Key: high 32 = order-flipped score (descending), low 32 = reference flat index
// i = pos*9 + a (ascending tie-break) -> ascending u64 sort == stable top_k order.
__global__ void k_scores(const float* __restrict__ sm, const float* __restrict__ bd,
                         const float* __restrict__ info, u64* __restrict__ keys) {
  int gid = blockIdx.x * 256 + threadIdx.x;
  int b = gid / NPB;
  int t = gid - b * NPB;
  int a = t / HWC;
  int pos = t - a * HWC;
  float imH = info[b*3+0], imW = info[b*3+1], ms = 16.0f * info[b*3+2];
  float s = sm[((size_t)(b * 2 * NA) + NA + a) * HWC + (size_t)pos];
  float x1, y1, x2, y2; bool keep;
  box_from_deltas(bd, b, a, pos, imH, imW, ms, x1, y1, x2, y2, keep);
  if (!keep) s = __uint_as_float(0xFF800000u);  // -inf
  u32 su = __float_as_uint(s);
  u32 asc = (su & 0x80000000u) ? ~su : (su | 0x80000000u);
  u32 desc = ~asc;
  u32 idx = (u32)(pos * NA + a);
  keys[gid] = ((u64)desc << 32) | (u64)idx;
}

// Radix-select pass: histogram of current candidate set (keys matching prefix).
__global__ void k_hist(const u64* __restrict__ keys, const u32* __restrict__ done,
                       const u64* __restrict__ prefix_arr, u32* __restrict__ hist,
                       int first, int shift, int width) {
  int img = blockIdx.y;
  if (done[img]) return;
  __shared__ u32 lh[NBIN];
  for (int i = threadIdx.x; i < NBIN; i += 256) lh[i] = 0;
  __syncthreads();
  u64 prefix = prefix_arr[img];
  const u64* kp = keys + (size_t)img * NPB + (size_t)blockIdx.x * 3840;
  u32 dmask = (1u << width) - 1u;
  if (first) {
    for (int j = 0; j < 15; j++) {
      u64 key = kp[j * 256 + threadIdx.x];
      atomicAdd(&lh[(u32)(key >> shift) & dmask], 1u);
    }
  } else {
    int hs = shift + width;
    for (int j = 0; j < 15; j++) {
      u64 key = kp[j * 256 + threadIdx.x];
      if ((key >> hs) == prefix) atomicAdd(&lh[(u32)(key >> shift) & dmask], 1u);
    }
  }
  __syncthreads();
  u32* gh = hist + img * NBIN;
  for (int i = threadIdx.x; i < NBIN; i += 256) { u32 v = lh[i]; if (v) atomicAdd(&gh[i], v); }
}

// Pick the bin containing the k-th smallest; stop early once selecting the whole
// boundary bin keeps M = (#keys <= threshold) within SEL_CAP (always true by pass 6).
__global__ void k_select(u32* __restrict__ hist, u64* __restrict__ prefix_arr, u32* __restrict__ kth,
                         u32* __restrict__ done, u64* __restrict__ thresh, int shift, int width) {
  int img = blockIdx.x;
  if (done[img]) return;
  int tid = threadIdx.x;
  __shared__ u32 sc[256];
  u32* h = hist + img * NBIN;
  u32 loc[8];
  u32 tot = 0;
  for (int j = 0; j < 8; j++) { loc[j] = h[tid * 8 + j]; tot += loc[j]; }
  for (int j = 0; j < 8; j++) h[tid * 8 + j] = 0;  // reset for next pass
  sc[tid] = tot;
  __syncthreads();
  for (int off = 1; off < 256; off <<= 1) {
    u32 v = sc[tid];
    u32 add = (tid >= off) ? sc[tid - off] : 0u;
    __syncthreads();
    sc[tid] = v + add;
    __syncthreads();
  }
  u32 incl = sc[tid];
  u32 excl = incl - tot;
  u32 k = kth[img];
  if (k > excl && k <= incl) {
    u32 run = excl;
    for (int j = 0; j < 8; j++) {
      run += loc[j];
      if (run >= k) {
        u32 bin = (u32)(tid * 8 + j);
        u32 below = run - loc[j];
        u32 cnt = loc[j];
        u32 knew = k - below;
        u64 pfull = (prefix_arr[img] << width) | (u64)bin;
        u32 M = (u32)PRE_N - knew + cnt;   // #keys <= (pfull|ones) globally
        if (M <= SEL_CAP) {
          done[img] = 1;
          u64 lowmask = (shift > 0) ? ((1ULL << shift) - 1ULL) : 0ULL;
          thresh[img] = (pfull << shift) | lowmask;
        } else {
          prefix_arr[img] = pfull;
          kth[img] = knew;
        }
        break;
      }
    }
  }
}

// Block-aggregated compaction: one global atomicAdd per BLOCK. Threads count
// picks, LDS-scan for intra-block offsets, leader reserves a range, then each
// thread re-reads its (L1/L2-hot) keys and writes picks at its offset.
// Within-image order is arbitrary; the sort establishes exact order afterwards.
__global__ void k_compact(const u64* __restrict__ keys, const u64* __restrict__ thresh,
                          u32* __restrict__ selcnt, u64* __restrict__ sel) {
  int img = blockIdx.y;
  int tid = threadIdx.x;
  u64 T = thresh[img];
  const u64* kp = keys + (size_t)img * NPB + (size_t)blockIdx.x * 3840;
  u32 mycnt = 0;
  #pragma unroll
  for (int j = 0; j < 15; j++) {
    u64 key = kp[j * 256 + tid];
    if (key <= T) mycnt++;
  }
  __shared__ u32 sc[256];
  __shared__ u32 sbase;
  sc[tid] = mycnt;
  __syncthreads();
  for (int off = 1; off < 256; off <<= 1) {
    u32 v = sc[tid];
    u32 add = (tid >= off) ? sc[tid - off] : 0u;
    __syncthreads();
    sc[tid] = v + add;
    __syncthreads();
  }
  if (tid == 255 && sc[255] > 0) sbase = atomicAdd(&selcnt[img], sc[255]);
  __syncthreads();
  if (mycnt == 0) return;
  u32 myoff = sbase + sc[tid] - mycnt;
  u64* sp = sel + (size_t)img * SEL_CAP;
  u32 c = 0;
  #pragma unroll
  for (int j = 0; j < 15; j++) {
    u64 key = kp[j * 256 + tid];
    if (key <= T) {
      u32 p = myoff + c;
      if (p < SEL_CAP) sp[p] = key;
      c++;
    }
  }
}

// Stage 1: sort each 1024-key chunk ascending in LDS (8 chunks/image x 16 images
// = 128 blocks -> full-chip occupancy instead of 16 blocks). Pads i>=cnt with ~0.
__global__ void __launch_bounds__(256) k_sort1(u64* __restrict__ sel, const u32* __restrict__ selcnt) {
  __shared__ u64 s[1024];
  int img = blockIdx.y, c = blockIdx.x, tid = threadIdx.x;
  u32 cnt = selcnt[img]; if (cnt > SEL_CAP) cnt = SEL_CAP;
  u64* sp = sel + (size_t)img * SEL_CAP + (size_t)c * 1024;
  int gbase = c * 1024;
  for (int i = tid; i < 1024; i += 256) s[i] = ((u32)(gbase + i) < cnt) ? sp[i] : ~0ULL;
  __syncthreads();
  for (int k = 2; k <= 1024; k <<= 1) {
    for (int j = k >> 1; j > 0; j >>= 1) {
      for (int i = tid; i < 1024; i += 256) {
        int p = i ^ j;
        if (p > i) {
          u64 a = s[i], b = s[p];
          bool up = ((i & k) == 0);
          if (up ? (a > b) : (a < b)) { s[i] = b; s[p] = a; }
        }
      }
      __syncthreads();
    }
  }
  for (int i = tid; i < 1024; i += 256) sp[i] = s[i];
}

// Stage 2: merge 8 sorted 1024-runs -> 8192 via 3 merge-path levels in LDS.
// Each thread binary-searches its diagonal and merges 8 outputs in registers;
// 2 barriers per level (6 total, vs 91 for the monolithic bitonic).
__global__ void __launch_bounds__(1024) k_sort2(const u64* __restrict__ sel,
                                                u32* __restrict__ sidx, u32* __restrict__ nvalid) {
  __shared__ u64 s[SEL_CAP];   // 64 KiB
  int img = blockIdx.x;
  int tid = threadIdx.x;
  const u64* sp = sel + (size_t)img * SEL_CAP;
  for (int i = tid; i < SEL_CAP; i += 1024) s[i] = sp[i];
  __syncthreads();
  int d0 = tid * 8;
  for (int L = 1024; L < SEL_CAP; L <<= 1) {
    int pairBase = d0 & ~(2 * L - 1);
    int d = d0 - pairBase;
    const u64* A = s + pairBase;
    const u64* B = s + pairBase + L;
    int lo = d - L; if (lo < 0) lo = 0;
    int hi = (d < L) ? d : L;
    while (lo < hi) {
      int mid = (lo + hi) >> 1;
      if (A[mid] <= B[d - 1 - mid]) lo = mid + 1; else hi = mid;
    }
    int ia = lo, ib = d - lo;
    u64 o[8];
    #pragma unroll
    for (int k = 0; k < 8; k++) {
      bool ta = (ib >= L) || (ia < L && A[ia] <= B[ib]);
      o[k] = ta ? A[ia++] : B[ib++];
    }
    __syncthreads();
    #pragma unroll
    for (int k = 0; k < 8; k++) s[d0 + k] = o[k];
    __syncthreads();
  }
  for (int r = tid; r < PRE_N; r += 1024) {
    u64 key = s[r];
    u32 hi32 = (u32)(key >> 32);
    bool valid = hi32 < 0xFF800000u;            // score > -inf
    sidx[img * PRE_N + r] = valid ? (u32)key : 0xFFFFFFFFu;
    bool pv = (r == 0) ? true : (((u32)(s[r - 1] >> 32)) < 0xFF800000u);
    if (!valid && pv) nvalid[img] = (u32)r;     // first invalid rank
  }
}

__global__ void k_gather(const float* __restrict__ bd, const float* __restrict__ info,
                         const u32* __restrict__ sidx, float4* __restrict__ boxes) {
  int gid = blockIdx.x * 256 + threadIdx.x;
  if (gid >= NBATCH * PRE_N) return;
  int img = gid / PRE_N;
  u32 iv = sidx[gid];
  float4 bx = make_float4(0.f, 0.f, 0.f, 0.f);
  if (iv != 0xFFFFFFFFu) {
    int i = (int)iv;
    int a = i % NA;
    int pos = i / NA;
    float imH = info[img*3+0], imW = info[img*3+1], ms = 16.0f * info[img*3+2];
    float x1, y1, x2, y2; bool keep;
    box_from_deltas(bd, img, a, pos, imH, imW, ms, x1, y1, x2, y2, keep);
    bx = make_float4(x1, y1, x2, y2);
  }
  boxes[gid] = bx;
}

// Lazy batched greedy NMS: batch of 64 candidates tested vs kept list (split over
// 4 waves), then wave-0 serial pass resolves within-batch dependencies via ballot.
__global__ void __launch_bounds__(256) k_nms(const float4* __restrict__ boxes,
                                             const u32* __restrict__ nvalid_arr,
                                             float* __restrict__ out) {
  int img = blockIdx.x;
  __shared__ float kx1[POST_N], ky1[POST_N], kx2[POST_N], ky2[POST_N], ka[POST_N];
  __shared__ float cx1[64], cy1[64], cx2[64], cy2[64], ca[64];
  __shared__ u64 supw[4];
  __shared__ int sh_nkept;
  int tid = threadIdx.x;
  int lane = tid & 63;
  int wv = tid >> 6;
  int nvalid = (int)nvalid_arr[img];
  if (nvalid > PRE_N) nvalid = PRE_N;
  if (tid == 0) sh_nkept = 0;
  __syncthreads();
  const float4* bb = boxes + (size_t)img * PRE_N;
  for (int base = 0; base < nvalid; base += 64) {
    if (sh_nkept >= POST_N) break;
    int bn = nvalid - base; if (bn > 64) bn = 64;
    if (tid < bn) {
      float4 c = bb[base + tid];
      cx1[tid] = c.x; cy1[tid] = c.y; cx2[tid] = c.z; cy2[tid] = c.w;
      ca[tid] = (c.z - c.x + 1.0f) * (c.w - c.y + 1.0f);
    }
    __syncthreads();
    int nk = sh_nkept;
    bool sup;
    if (lane < bn) {
      sup = false;
      float X1 = cx1[lane], Y1 = cy1[lane], X2 = cx2[lane], Y2 = cy2[lane], A0 = ca[lane];
      for (int j = wv; j < nk; j += 4) {
        float xx1 = fmaxf(kx1[j], X1);
        float yy1 = fmaxf(ky1[j], Y1);
        float xx2 = fminf(kx2[j], X2);
        float yy2 = fminf(ky2[j], Y2);
        float iw = fmaxf(0.0f, xx2 - xx1 + 1.0f);
        float ih = fmaxf(0.0f, yy2 - yy1 + 1.0f);
        float inter = iw * ih;
        float iou = inter / ((ka[j] + A0) - inter);   // same operand order as reference
        if (iou > 0.7f) { sup = true; break; }
      }
    } else {
      sup = true;
    }
    u64 m = __ballot(sup);
    if (lane == 0) supw[wv] = m;
    __syncthreads();
    if (wv == 0) {
      u64 live = ~(supw[0] | supw[1] | supw[2] | supw[3]);
      int nkept = sh_nkept;
      while (live && nkept < POST_N) {
        int c = __ffsll((long long)live) - 1;
        live &= live - 1ULL;
        float X1 = cx1[c], Y1 = cy1[c], X2 = cx2[c], Y2 = cy2[c], A0 = ca[c];
        if (lane == 0) {
          kx1[nkept] = X1; ky1[nkept] = Y1; kx2[nkept] = X2; ky2[nkept] = Y2; ka[nkept] = A0;
          float* o = out + ((size_t)img * POST_N + nkept) * 5;
          o[0] = (float)img; o[1] = X1; o[2] = Y1; o[3] = X2; o[4] = Y2;
        }
        nkept++;
        bool s2 = false;
        if ((live >> lane) & 1ULL) {
          float xx1 = fmaxf(X1, cx1[lane]);
          float yy1 = fmaxf(Y1, cy1[lane]);
          float xx2 = fminf(X2, cx2[lane]);
          float yy2 = fminf(Y2, cy2[lane]);
          float iw = fmaxf(0.0f, xx2 - xx1 + 1.0f);
          float ih = fmaxf(0.0f, yy2 - yy1 + 1.0f);
          float inter = iw * ih;
          float iou = inter / ((A0 + ca[lane]) - inter);
          s2 = iou > 0.7f;
        }
        live &= ~__ballot(s2);
      }
      if (lane == 0) sh_nkept = nkept;
    }
    __syncthreads();
  }
  int fk = sh_nkept;
  for (int r = fk + tid; r < POST_N; r += 256) {
    float* o = out + ((size_t)img * POST_N + r) * 5;
    o[0] = (float)img; o[1] = 0.f; o[2] = 0.f; o[3] = 0.f; o[4] = 0.f;
  }
}

extern "C" void kernel_launch(void* const* d_in, const int* in_sizes, int n_in,
                              void* d_out, int out_size, void* d_ws, size_t ws_size,
                              hipStream_t stream) {
  const float* sm   = (const float*)d_in[0];
  const float* bd   = (const float*)d_in[1];
  const float* info = (const float*)d_in[2];
  float* out = (float*)d_out;
  char* ws = (char*)d_ws;

  size_t off = 0;
  auto alloc = [&](size_t bytes) { size_t o = off; off += (bytes + 255) & ~(size_t)255; return o; };
  u64* keys     = (u64*)(ws + alloc((size_t)NBATCH * NPB * 8));       // ~29.5 MB
  u32* hist     = (u32*)(ws + alloc((size_t)NBATCH * NBIN * 4));
  u64* prefix   = (u64*)(ws + alloc(NBATCH * 8));
  u32* kth      = (u32*)(ws + alloc(NBATCH * 4));
  u32* done     = (u32*)(ws + alloc(NBATCH * 4));
  u32* selcnt   = (u32*)(ws + alloc(NBATCH * 4));
  u32* nvalid   = (u32*)(ws + alloc(NBATCH * 4));
  u64* thresh   = (u64*)(ws + alloc(NBATCH * 8));
  u64* sel      = (u64*)(ws + alloc((size_t)NBATCH * SEL_CAP * 8));
  u32* sidx     = (u32*)(ws + alloc((size_t)NBATCH * PRE_N * 4));
  float4* boxes = (float4*)(ws + alloc((size_t)NBATCH * PRE_N * 16));
  (void)ws_size; (void)in_sizes; (void)n_in; (void)out_size;

  hipLaunchKernelGGL(k_init, dim3(128), dim3(256), 0, stream, hist, prefix, kth, done, selcnt, nvalid);
  hipLaunchKernelGGL(k_scores, dim3(14400), dim3(256), 0, stream, sm, bd, info, keys);
  const int shifts[6] = {53, 42, 31, 20, 9, 0};
  const int widths[6] = {11, 11, 11, 11, 11, 9};
  for (int p = 0; p < 6; p++) {
    hipLaunchKernelGGL(k_hist, dim3(60, 16), dim3(256), 0, stream,
                       keys, done, prefix, hist, (p == 0) ? 1 : 0, shifts[p], widths[p]);
    hipLaunchKernelGGL(k_select, dim3(16), dim3(256), 0, stream,
                       hist, prefix, kth, done, thresh, shifts[p], widths[p]);
  }
  hipLaunchKernelGGL(k_compact, dim3(60, 16), dim3(256), 0, stream, keys, thresh, selcnt, sel);
  hipLaunchKernelGGL(k_sort1, dim3(8, 16), dim3(256), 0, stream, sel, selcnt);
  hipLaunchKernelGGL(k_sort2, dim3(16), dim3(1024), 0, stream, sel, sidx, nvalid);
  hipLaunchKernelGGL(k_gather, dim3(375), dim3(256), 0, stream, bd, info, sidx, boxes);
  hipLaunchKernelGGL(k_nms, dim3(16), dim3(256), 0, stream, boxes, nvalid, out);
}

// Round 4
// 318.285 us; speedup vs baseline: 2.9021x; 1.0143x over previous
//
#include <hip/hip_runtime.h>
#include <cstdint>
#include <cstddef>

typedef unsigned int u32;
typedef unsigned long long u64;

#define NBATCH 16
#define NA 9
#define HF 160
#define WF 160
#define HWC (HF*WF)          // 25600
#define NPB (NA*HWC)         // 230400 anchors per image
#define PRE_N 6000
#define POST_N 300
#define SEL_CAP 8192
#define NBIN 2048            // fallback radix bins
#define UNI_BINS 2048        // uniform score bins (2^11; s*2048 and q/2048 are exact fp32)
#define NMS_W 8              // waves in k_nms (512 threads)

// Anchor constants derived exactly from generate_anchors(16,[0.5,1,2],[8,16,32]):
// all anchors have center (8,8) at cell (0,0); only w/h differ.
__constant__ float c_AW[9] = {184.f,368.f,736.f,128.f,256.f,512.f,88.f,176.f,352.f};
__constant__ float c_AH[9] = {96.f,192.f,384.f,128.f,256.f,512.f,176.f,352.f,704.f};

__device__ __forceinline__ void box_from_deltas(
    const float* __restrict__ bd, int b, int a, int pos,
    float imH, float imW, float ms,
    float& x1, float& y1, float& x2, float& y2, bool& keep)
{
  int y = pos / WF;
  int x = pos - y * WF;
  size_t base = ((size_t)(b * 4 * NA) + 4 * a) * HWC + (size_t)pos;
  float d0 = bd[base];
  float d1 = bd[base + HWC];
  float d2 = bd[base + 2 * HWC];
  float d3 = bd[base + 3 * HWC];
  float aw = c_AW[a], ah = c_AH[a];
  float acx = (float)x * 16.0f + 8.0f;
  float acy = (float)y * 16.0f + 8.0f;
  float pcx = d0 * aw + acx;
  float pcy = d1 * ah + acy;
  float pw  = expf(d2) * aw;
  float ph  = expf(d3) * ah;
  x1 = fminf(fmaxf(pcx - 0.5f * pw, 0.0f), imW - 1.0f);
  y1 = fminf(fmaxf(pcy - 0.5f * ph, 0.0f), imH - 1.0f);
  x2 = fminf(fmaxf(pcx + 0.5f * pw, 0.0f), imW - 1.0f);
  y2 = fminf(fmaxf(pcy + 0.5f * ph, 0.0f), imH - 1.0f);
  keep = ((x2 - x1 + 1.0f) >= ms) && ((y2 - y1 + 1.0f) >= ms);
}

__device__ __forceinline__ u32 desc_enc(float s) {
  u32 su = __float_as_uint(s);
  u32 asc = (su & 0x80000000u) ? ~su : (su | 0x80000000u);
  return ~asc;
}

// keys + single-pass uniform-bin histogram (fused; was k_scores + 6x k_hist).
// Key: high 32 = order-flipped score (descending), low 32 = reference flat index
// i = pos*9 + a -> ascending u64 order == stable top_k order. Bin: 2047 - floor(s*2048)
// (exact fp32 mapping; -inf -> cvt saturates negative -> bin 2047).
__global__ void __launch_bounds__(256) k_scores_hist(
    const float* __restrict__ sm, const float* __restrict__ bd,
    const float* __restrict__ info, u64* __restrict__ keys, u32* __restrict__ hist) {
  __shared__ u32 lh[UNI_BINS];
  int img = blockIdx.x / 60;
  int slice = blockIdx.x % 60;
  int tid = threadIdx.x;
  for (int i = tid; i < UNI_BINS; i += 256) lh[i] = 0;
  __syncthreads();
  float imH = info[img*3+0], imW = info[img*3+1], ms = 16.0f * info[img*3+2];
  for (int j = 0; j < 15; j++) {
    int t = slice * 3840 + j * 256 + tid;
    int a = t / HWC;
    int pos = t - a * HWC;
    float s = sm[((size_t)(img * 2 * NA) + NA + a) * HWC + (size_t)pos];
    float x1, y1, x2, y2; bool keep;
    box_from_deltas(bd, img, a, pos, imH, imW, ms, x1, y1, x2, y2, keep);
    if (!keep) s = __uint_as_float(0xFF800000u);  // -inf
    u32 idx = (u32)(pos * NA + a);
    keys[(size_t)img * NPB + t] = ((u64)desc_enc(s) << 32) | (u64)idx;
    int q = (int)floorf(s * (float)UNI_BINS);
    q = q < 0 ? 0 : (q > UNI_BINS - 1 ? UNI_BINS - 1 : q);
    atomicAdd(&lh[(UNI_BINS - 1) - q], 1u);
  }
  __syncthreads();
  u32* gh = hist + img * UNI_BINS;
  for (int i = tid; i < UNI_BINS; i += 256) { u32 v = lh[i]; if (v) atomicAdd(&gh[i], v); }
}

// Select threshold from the uniform hist (1 pass, exact: bin boundary = exact
// float score = exact key threshold). If the boundary bin would overflow
// SEL_CAP or sits in the -inf bin, run an exact in-block 6-pass radix fallback
// (pathological-tie insurance; no-op on benign data).
__global__ void __launch_bounds__(256) k_select(
    const u64* __restrict__ keys, const u32* __restrict__ hist, u64* __restrict__ thresh_arr) {
  int img = blockIdx.x, tid = threadIdx.x;
  __shared__ u32 sc[256];
  __shared__ u32 lh[NBIN];
  __shared__ u64 sh_thresh;
  __shared__ int sh_state;
  __shared__ u64 sh_prefix;
  __shared__ u32 sh_kth;
  const u32* gh = hist + img * UNI_BINS;
  u32 loc[8]; u32 tot = 0;
  for (int j = 0; j < 8; j++) { loc[j] = gh[tid * 8 + j]; tot += loc[j]; }
  if (tid == 0) { sh_state = 0; sh_prefix = 0; sh_kth = PRE_N; }
  sc[tid] = tot;
  __syncthreads();
  for (int off = 1; off < 256; off <<= 1) {
    u32 v = sc[tid]; u32 a = (tid >= off) ? sc[tid - off] : 0u;
    __syncthreads(); sc[tid] = v + a; __syncthreads();
  }
  u32 incl = sc[tid], excl = incl - tot;
  if (PRE_N > excl && PRE_N <= incl) {
    u32 run = excl;
    for (int j = 0; j < 8; j++) {
      run += loc[j];
      if (run >= PRE_N) {
        int b = tid * 8 + j;
        u32 M = run;  // full cumulative through boundary bin
        if (b < UNI_BINS - 1 && M <= SEL_CAP) {
          float sb = (float)(UNI_BINS - 1 - b) * (1.0f / (float)UNI_BINS);
          sh_thresh = ((u64)desc_enc(sb) << 32) | 0xFFFFFFFFull;
          sh_state = 1;
        }
        break;
      }
    }
  }
  __syncthreads();
  if (!sh_state) {
    const u64* kp = keys + (size_t)img * NPB;
    const int shifts[6] = {53, 42, 31, 20, 9, 0};
    const int widths[6] = {11, 11, 11, 11, 11, 9};
    for (int p = 0; p < 6; p++) {
      if (sh_state) break;
      for (int i = tid; i < NBIN; i += 256) lh[i] = 0;
      __syncthreads();
      u64 prefix = sh_prefix; u32 kth = sh_kth;
      int shift = shifts[p], width = widths[p];
      u32 nb = 1u << width;
      int hs = shift + width;
      for (int i = tid; i < NPB; i += 256) {
        u64 key = kp[i];
        bool m = (p == 0) || ((key >> hs) == prefix);
        if (m) atomicAdd(&lh[(u32)(key >> shift) & (nb - 1u)], 1u);
      }
      __syncthreads();
      u32 l2[8]; u32 t2 = 0;
      for (int j = 0; j < 8; j++) {
        u32 b = (u32)(tid * 8 + j);
        u32 v = (b < nb) ? lh[b] : 0u;
        l2[j] = v; t2 += v;
      }
      sc[tid] = t2; __syncthreads();
      for (int off = 1; off < 256; off <<= 1) {
        u32 v = sc[tid]; u32 a = (tid >= off) ? sc[tid - off] : 0u;
        __syncthreads(); sc[tid] = v + a; __syncthreads();
      }
      u32 incl2 = sc[tid], excl2 = incl2 - t2;
      if (kth > excl2 && kth <= incl2) {
        u32 run = excl2;
        for (int j = 0; j < 8; j++) {
          run += l2[j];
          if (run >= kth) {
            u32 bin = (u32)(tid * 8 + j);
            u32 below = run - l2[j];
            u32 cnt = l2[j];
            u32 knew = kth - below;
            u64 pfull = (prefix << width) | (u64)bin;
            u32 M = (u32)PRE_N - knew + cnt;
            if (M <= SEL_CAP) {
              u64 lowmask = (shift > 0) ? ((1ULL << shift) - 1ULL) : 0ULL;
              sh_thresh = (pfull << shift) | lowmask;
              sh_state = 1;
            } else {
              sh_prefix = pfull; sh_kth = knew;
            }
            break;
          }
        }
      }
      __syncthreads();
    }
  }
  if (tid == 0) thresh_arr[img] = sh_thresh;
}

// Block-aggregated compaction: one global atomicAdd per block.
__global__ void k_compact(const u64* __restrict__ keys, const u64* __restrict__ thresh,
                          u32* __restrict__ selcnt, u64* __restrict__ sel) {
  int img = blockIdx.y;
  int tid = threadIdx.x;
  u64 T = thresh[img];
  const u64* kp = keys + (size_t)img * NPB + (size_t)blockIdx.x * 3840;
  u32 mycnt = 0;
  #pragma unroll
  for (int j = 0; j < 15; j++) {
    u64 key = kp[j * 256 + tid];
    if (key <= T) mycnt++;
  }
  __shared__ u32 sc[256];
  __shared__ u32 sbase;
  sc[tid] = mycnt;
  __syncthreads();
  for (int off = 1; off < 256; off <<= 1) {
    u32 v = sc[tid];
    u32 add = (tid >= off) ? sc[tid - off] : 0u;
    __syncthreads();
    sc[tid] = v + add;
    __syncthreads();
  }
  if (tid == 255 && sc[255] > 0) sbase = atomicAdd(&selcnt[img], sc[255]);
  __syncthreads();
  if (mycnt == 0) return;
  u32 myoff = sbase + sc[tid] - mycnt;
  u64* sp = sel + (size_t)img * SEL_CAP;
  u32 c = 0;
  #pragma unroll
  for (int j = 0; j < 15; j++) {
    u64 key = kp[j * 256 + tid];
    if (key <= T) {
      u32 p = myoff + c;
      if (p < SEL_CAP) sp[p] = key;
      c++;
    }
  }
}

// Fused: chunk bitonic (within-1024 phases of the 8192 network) + merge-path
// merge (3 levels) + rank->box gather epilogue. One kernel instead of three.
__global__ void __launch_bounds__(1024) k_sortmg(
    const u64* __restrict__ sel, const u32* __restrict__ selcnt,
    const float* __restrict__ bd, const float* __restrict__ info,
    float4* __restrict__ boxes, u32* __restrict__ nvalid) {
  __shared__ u64 s[SEL_CAP];   // 64 KiB
  __shared__ int sh_nv;
  int img = blockIdx.x;
  int tid = threadIdx.x;
  u32 cnt = selcnt[img];
  if (cnt > SEL_CAP) cnt = SEL_CAP;
  const u64* sp = sel + (size_t)img * SEL_CAP;
  if (tid == 0) sh_nv = PRE_N;
  for (int i = tid; i < SEL_CAP; i += 1024) s[i] = (i < (int)cnt) ? sp[i] : ~0ULL;
  __syncthreads();
  // bitonic phases k=2..1024: partners stay within 1024-chunks; direction from
  // local index so every chunk ends ascending.
  for (int k = 2; k <= 1024; k <<= 1) {
    for (int j = k >> 1; j > 0; j >>= 1) {
      for (int i = tid; i < SEL_CAP; i += 1024) {
        int p = i ^ j;
        if (p > i) {
          u64 a = s[i], b = s[p];
          int il = i & 1023;
          bool up = ((il & k) == 0);
          if (up ? (a > b) : (a < b)) { s[i] = b; s[p] = a; }
        }
      }
      __syncthreads();
    }
  }
  // merge-path: 1024 -> 2048 -> 4096 -> 8192
  int d0 = tid * 8;
  for (int L = 1024; L < SEL_CAP; L <<= 1) {
    int pairBase = d0 & ~(2 * L - 1);
    int d = d0 - pairBase;
    const u64* A = s + pairBase;
    const u64* B = s + pairBase + L;
    int lo = d - L; if (lo < 0) lo = 0;
    int hi = (d < L) ? d : L;
    while (lo < hi) {
      int mid = (lo + hi) >> 1;
      if (A[mid] <= B[d - 1 - mid]) lo = mid + 1; else hi = mid;
    }
    int ia = lo, ib = d - lo;
    u64 o[8];
    #pragma unroll
    for (int k = 0; k < 8; k++) {
      bool ta = (ib >= L) || (ia < L && A[ia] <= B[ib]);
      o[k] = ta ? A[ia++] : B[ib++];
    }
    __syncthreads();
    #pragma unroll
    for (int k = 0; k < 8; k++) s[d0 + k] = o[k];
    __syncthreads();
  }
  // epilogue: validity boundary + box gather
  float imH = info[img*3+0], imW = info[img*3+1], ms = 16.0f * info[img*3+2];
  for (int r = tid; r < PRE_N; r += 1024) {
    u64 key = s[r];
    bool valid = (u32)(key >> 32) < 0xFF800000u;    // score > -inf
    if (!valid) atomicMin(&sh_nv, r);
    float4 bx = make_float4(0.f, 0.f, 0.f, 0.f);
    if (valid) {
      int idx = (int)(u32)key;
      int a = idx % NA;
      int pos = idx / NA;
      float x1, y1, x2, y2; bool keep;
      box_from_deltas(bd, img, a, pos, imH, imW, ms, x1, y1, x2, y2, keep);
      bx = make_float4(x1, y1, x2, y2);
    }
    boxes[(size_t)img * PRE_N + r] = bx;
  }
  __syncthreads();
  if (tid == 0) nvalid[img] = (u32)sh_nv;
}

// NMS: batched-lazy greedy with (a) precomputed within-batch 64x64 suppression
// masks (serial chain = ffs + shfl + and), (b) conservative packed-u8 log-area
// gate on the kept-list scan (iou>0.7 => area ratio < 1/0.7), (c) exact
// divide-free compare (fmaf sign exact; IEEE divide only in the borderline
// band), (d) double-buffered candidate load overlapping the serial phase.
__global__ void __launch_bounds__(512) k_nms(const float4* __restrict__ boxes,
                                             const u32* __restrict__ nvalid_arr,
                                             float* __restrict__ out) {
  __shared__ float4 kbox[POST_N];
  __shared__ float karea[POST_N];
  __shared__ u64 kcodeW[(POST_N + 7) / 8];
  __shared__ float4 cb[2][64];
  __shared__ float car[2][64];
  __shared__ int cint[2][64];
  __shared__ u64 winm[2][64];
  __shared__ u64 supw[2][NMS_W];
  __shared__ int sh_nkept;
  int img = blockIdx.x;
  int tid = threadIdx.x;
  int lane = tid & 63;
  int wv = tid >> 6;
  int nvalid = (int)nvalid_arr[img];
  if (nvalid > PRE_N) nvalid = PRE_N;
  const float4* bb = boxes + (size_t)img * PRE_N;
  if (tid == 0) sh_nkept = 0;
  if (tid < 64) {
    float4 c = (tid < nvalid) ? bb[tid] : make_float4(0.f, 0.f, 0.f, 0.f);
    cb[0][tid] = c;
    float A = (c.z - c.x + 1.0f) * (c.w - c.y + 1.0f);
    car[0][tid] = A;
    cint[0][tid] = (int)rintf(8.0f * log2f(A));
  } else if (tid < 128) {
    winm[0][tid - 64] = 0;
  } else if (tid < 128 + NMS_W) {
    supw[0][tid - 128] = 0;
  }
  __syncthreads();
  int pb = 0;
  for (int base = 0; base < nvalid; base += 64, pb ^= 1) {
    int nk = sh_nkept;
    if (nk >= POST_N) break;
    int bn = nvalid - base; if (bn > 64) bn = 64;
    // ---- phase A: vs-kept tests + within-batch pair masks ----
    bool sup;
    u64 wpart = 0;
    {
      bool inb = lane < bn;
      sup = !inb;
      if (inb) {
        float4 C = cb[pb][lane];
        float A0 = car[pb][lane];
        int myc = cint[pb][lane];
        int nw = (nk + 7) >> 3;
        for (int jw = wv; jw < nw && !sup; jw += NMS_W) {
          u64 w = kcodeW[jw];
          int jbase = jw << 3;
          int jm = nk - jbase; if (jm > 8) jm = 8;
          for (int k = 0; k < jm; k++) {
            int d = (int)((w >> (k * 8)) & 0xFFu) - myc;
            if (d > 5 || d < -5) continue;          // conservative area-ratio gate
            int j = jbase + k;
            float4 K = kbox[j];
            float xx1 = fmaxf(K.x, C.x);
            float yy1 = fmaxf(K.y, C.y);
            float xx2 = fminf(K.z, C.z);
            float yy2 = fminf(K.w, C.w);
            float iw = fmaxf(0.0f, xx2 - xx1 + 1.0f);
            float ih = fmaxf(0.0f, yy2 - yy1 + 1.0f);
            float inter = iw * ih;
            float uni = (karea[j] + A0) - inter;    // reference operand order
            float ss = fmaf(0.7f, uni, -inter);
            bool sp;
            if (fabsf(ss) <= uni * 1e-6f) sp = (inter / uni > 0.7f);
            else sp = (ss < 0.0f);
            if (sp) { sup = true; break; }
          }
        }
        for (int j = lane + 1 + wv; j < bn; j += NMS_W) {
          float Aj = car[pb][j];
          if (Aj <= 0.6999f * A0 || A0 <= 0.6999f * Aj) continue;
          float4 J = cb[pb][j];
          float xx1 = fmaxf(C.x, J.x);
          float yy1 = fmaxf(C.y, J.y);
          float xx2 = fminf(C.z, J.z);
          float yy2 = fminf(C.w, J.w);
          float iw = fmaxf(0.0f, xx2 - xx1 + 1.0f);
          float ih = fmaxf(0.0f, yy2 - yy1 + 1.0f);
          float inter = iw * ih;
          float uni = (A0 + Aj) - inter;            // i (earlier) area first
          float ss = fmaf(0.7f, uni, -inter);
          bool sp;
          if (fabsf(ss) <= uni * 1e-6f) sp = (inter / uni > 0.7f);
          else sp = (ss < 0.0f);
          if (sp) wpart |= 1ULL << j;
        }
      }
    }
    u64 bm = __ballot(sup);
    if (lane == 0) supw[pb][wv] = bm;
    if (wpart) atomicOr(&winm[pb][lane], wpart);
    __syncthreads();
    // ---- phase B/C (wave 0) | prefetch next batch (waves 1-2) ----
    if (wv == 0) {
      u64 so = (lane < NMS_W) ? supw[pb][lane] : 0ULL;
      so |= __shfl_xor(so, 1);
      so |= __shfl_xor(so, 2);
      so |= __shfl_xor(so, 4);
      so = __shfl(so, 0);
      u64 validm = (bn >= 64) ? ~0ULL : ((1ULL << bn) - 1ULL);
      u64 wm = winm[pb][lane];
      u64 live = validm & ~so;
      u64 km = 0;
      int cnt = nk;
      while (live && cnt < POST_N) {
        int c = __ffsll((long long)live) - 1;
        km |= 1ULL << c;
        cnt++;
        u64 m = __shfl(wm, c);
        live &= ~m;
        live &= ~(1ULL << c);
      }
      if ((km >> lane) & 1ULL) {
        int rank = nk + __popcll(km & ((1ULL << lane) - 1ULL));
        float4 C = cb[pb][lane];
        kbox[rank] = C;
        karea[rank] = car[pb][lane];
        ((unsigned char*)kcodeW)[rank] = (unsigned char)cint[pb][lane];
        float* o = out + ((size_t)img * POST_N + rank) * 5;
        o[0] = (float)img; o[1] = C.x; o[2] = C.y; o[3] = C.z; o[4] = C.w;
      }
      if (lane == 0) sh_nkept = cnt;
    } else if (wv == 1) {
      int nb2 = base + 64;
      if (nb2 < nvalid) {
        int i = nb2 + lane;
        float4 c = (i < nvalid) ? bb[i] : make_float4(0.f, 0.f, 0.f, 0.f);
        cb[pb ^ 1][lane] = c;
        float A = (c.z - c.x + 1.0f) * (c.w - c.y + 1.0f);
        car[pb ^ 1][lane] = A;
        cint[pb ^ 1][lane] = (int)rintf(8.0f * log2f(A));
      }
    } else if (wv == 2) {
      winm[pb ^ 1][lane] = 0;
      if (lane < NMS_W) supw[pb ^ 1][lane] = 0;
    }
    __syncthreads();
  }
  int fk = sh_nkept;
  for (int r = fk + tid; r < POST_N; r += 512) {
    float* o = out + ((size_t)img * POST_N + r) * 5;
    o[0] = (float)img; o[1] = 0.f; o[2] = 0.f; o[3] = 0.f; o[4] = 0.f;
  }
}

extern "C" void kernel_launch(void* const* d_in, const int* in_sizes, int n_in,
                              void* d_out, int out_size, void* d_ws, size_t ws_size,
                              hipStream_t stream) {
  const float* sm   = (const float*)d_in[0];
  const float* bd   = (const float*)d_in[1];
  const float* info = (const float*)d_in[2];
  float* out = (float*)d_out;
  char* ws = (char*)d_ws;

  size_t off = 0;
  auto alloc = [&](size_t bytes) { size_t o = off; off += (bytes + 255) & ~(size_t)255; return o; };
  u64* keys     = (u64*)(ws + alloc((size_t)NBATCH * NPB * 8));        // ~29.5 MB
  size_t off_hist = alloc((size_t)NBATCH * UNI_BINS * 4);              // 128 KB
  u32* hist     = (u32*)(ws + off_hist);
  u32* selcnt   = (u32*)(ws + alloc(NBATCH * 4));                      // adjacent to hist
  size_t zero_end = off;
  u64* thresh   = (u64*)(ws + alloc(NBATCH * 8));
  u32* nvalid   = (u32*)(ws + alloc(NBATCH * 4));
  u64* sel      = (u64*)(ws + alloc((size_t)NBATCH * SEL_CAP * 8));    // 1 MB
  float4* boxes = (float4*)(ws + alloc((size_t)NBATCH * PRE_N * 16));  // 1.5 MB
  (void)ws_size; (void)in_sizes; (void)n_in; (void)out_size;

  hipMemsetAsync(ws + off_hist, 0, zero_end - off_hist, stream);       // hist + selcnt
  hipLaunchKernelGGL(k_scores_hist, dim3(960), dim3(256), 0, stream, sm, bd, info, keys, hist);
  hipLaunchKernelGGL(k_select, dim3(16), dim3(256), 0, stream, keys, hist, thresh);
  hipLaunchKernelGGL(k_compact, dim3(60, 16), dim3(256), 0, stream, keys, thresh, selcnt, sel);
  hipLaunchKernelGGL(k_sortmg, dim3(16), dim3(1024), 0, stream, sel, selcnt, bd, info, boxes, nvalid);
  hipLaunchKernelGGL(k_nms, dim3(16), dim3(512), 0, stream, boxes, nvalid, out);
}

// Round 5
// 257.406 us; speedup vs baseline: 3.5885x; 1.2365x over previous
//
#include <hip/hip_runtime.h>
#include <cstdint>
#include <cstddef>

typedef unsigned int u32;
typedef unsigned long long u64;

#define NBATCH 16
#define NA 9
#define HF 160
#define WF 160
#define HWC (HF*WF)          // 25600
#define NPB (NA*HWC)         // 230400 anchors per image
#define PRE_N 6000
#define POST_N 300
#define SEL_CAP 8192
#define NBIN 2048            // fallback radix bins
#define UNI_BINS 2048        // uniform score bins (2^11; s*2048 and q/2048 are exact fp32)
#define NMS_W 8              // waves in k_nms (512 threads)

// Anchor constants derived exactly from generate_anchors(16,[0.5,1,2],[8,16,32]):
// all anchors have center (8,8) at cell (0,0); only w/h differ.
__constant__ float c_AW[9] = {184.f,368.f,736.f,128.f,256.f,512.f,88.f,176.f,352.f};
__constant__ float c_AH[9] = {96.f,192.f,384.f,128.f,256.f,512.f,176.f,352.f,704.f};

__device__ __forceinline__ void box_from_deltas(
    const float* __restrict__ bd, int b, int a, int pos,
    float imH, float imW, float ms,
    float& x1, float& y1, float& x2, float& y2, bool& keep)
{
  int y = pos / WF;
  int x = pos - y * WF;
  size_t base = ((size_t)(b * 4 * NA) + 4 * a) * HWC + (size_t)pos;
  float d0 = bd[base];
  float d1 = bd[base + HWC];
  float d2 = bd[base + 2 * HWC];
  float d3 = bd[base + 3 * HWC];
  float aw = c_AW[a], ah = c_AH[a];
  float acx = (float)x * 16.0f + 8.0f;
  float acy = (float)y * 16.0f + 8.0f;
  float pcx = d0 * aw + acx;
  float pcy = d1 * ah + acy;
  float pw  = expf(d2) * aw;
  float ph  = expf(d3) * ah;
  x1 = fminf(fmaxf(pcx - 0.5f * pw, 0.0f), imW - 1.0f);
  y1 = fminf(fmaxf(pcy - 0.5f * ph, 0.0f), imH - 1.0f);
  x2 = fminf(fmaxf(pcx + 0.5f * pw, 0.0f), imW - 1.0f);
  y2 = fminf(fmaxf(pcy + 0.5f * ph, 0.0f), imH - 1.0f);
  keep = ((x2 - x1 + 1.0f) >= ms) && ((y2 - y1 + 1.0f) >= ms);
}

__device__ __forceinline__ u32 desc_enc(float s) {
  u32 su = __float_as_uint(s);
  u32 asc = (su & 0x80000000u) ? ~su : (su | 0x80000000u);
  return ~asc;
}

// keys + single-pass uniform-bin histogram (fused).
// Key: high 32 = order-flipped score (descending), low 32 = reference flat index
// i = pos*9 + a -> ascending u64 order == stable top_k order. Bin: 2047 - floor(s*2048)
// (exact fp32 mapping; -inf -> cvt saturates negative -> bin 2047).
__global__ void __launch_bounds__(256) k_scores_hist(
    const float* __restrict__ sm, const float* __restrict__ bd,
    const float* __restrict__ info, u64* __restrict__ keys, u32* __restrict__ hist) {
  __shared__ u32 lh[UNI_BINS];
  int img = blockIdx.x / 60;
  int slice = blockIdx.x % 60;
  int tid = threadIdx.x;
  for (int i = tid; i < UNI_BINS; i += 256) lh[i] = 0;
  __syncthreads();
  float imH = info[img*3+0], imW = info[img*3+1], ms = 16.0f * info[img*3+2];
  for (int j = 0; j < 15; j++) {
    int t = slice * 3840 + j * 256 + tid;
    int a = t / HWC;
    int pos = t - a * HWC;
    float s = sm[((size_t)(img * 2 * NA) + NA + a) * HWC + (size_t)pos];
    float x1, y1, x2, y2; bool keep;
    box_from_deltas(bd, img, a, pos, imH, imW, ms, x1, y1, x2, y2, keep);
    if (!keep) s = __uint_as_float(0xFF800000u);  // -inf
    u32 idx = (u32)(pos * NA + a);
    keys[(size_t)img * NPB + t] = ((u64)desc_enc(s) << 32) | (u64)idx;
    int q = (int)floorf(s * (float)UNI_BINS);
    q = q < 0 ? 0 : (q > UNI_BINS - 1 ? UNI_BINS - 1 : q);
    atomicAdd(&lh[(UNI_BINS - 1) - q], 1u);
  }
  __syncthreads();
  u32* gh = hist + img * UNI_BINS;
  for (int i = tid; i < UNI_BINS; i += 256) { u32 v = lh[i]; if (v) atomicAdd(&gh[i], v); }
}

// Select threshold from the uniform hist (1 pass, exact). If the boundary bin
// would overflow SEL_CAP or sits in the -inf bin, run an exact in-block 6-pass
// radix fallback (pathological-tie insurance; no-op on benign data).
__global__ void __launch_bounds__(256) k_select(
    const u64* __restrict__ keys, const u32* __restrict__ hist, u64* __restrict__ thresh_arr) {
  int img = blockIdx.x, tid = threadIdx.x;
  __shared__ u32 sc[256];
  __shared__ u32 lh[NBIN];
  __shared__ u64 sh_thresh;
  __shared__ int sh_state;
  __shared__ u64 sh_prefix;
  __shared__ u32 sh_kth;
  const u32* gh = hist + img * UNI_BINS;
  u32 loc[8]; u32 tot = 0;
  for (int j = 0; j < 8; j++) { loc[j] = gh[tid * 8 + j]; tot += loc[j]; }
  if (tid == 0) { sh_state = 0; sh_prefix = 0; sh_kth = PRE_N; }
  sc[tid] = tot;
  __syncthreads();
  for (int off = 1; off < 256; off <<= 1) {
    u32 v = sc[tid]; u32 a = (tid >= off) ? sc[tid - off] : 0u;
    __syncthreads(); sc[tid] = v + a; __syncthreads();
  }
  u32 incl = sc[tid], excl = incl - tot;
  if (PRE_N > excl && PRE_N <= incl) {
    u32 run = excl;
    for (int j = 0; j < 8; j++) {
      run += loc[j];
      if (run >= PRE_N) {
        int b = tid * 8 + j;
        u32 M = run;  // full cumulative through boundary bin
        if (b < UNI_BINS - 1 && M <= SEL_CAP) {
          float sb = (float)(UNI_BINS - 1 - b) * (1.0f / (float)UNI_BINS);
          sh_thresh = ((u64)desc_enc(sb) << 32) | 0xFFFFFFFFull;
          sh_state = 1;
        }
        break;
      }
    }
  }
  __syncthreads();
  if (!sh_state) {
    const u64* kp = keys + (size_t)img * NPB;
    const int shifts[6] = {53, 42, 31, 20, 9, 0};
    const int widths[6] = {11, 11, 11, 11, 11, 9};
    for (int p = 0; p < 6; p++) {
      if (sh_state) break;
      for (int i = tid; i < NBIN; i += 256) lh[i] = 0;
      __syncthreads();
      u64 prefix = sh_prefix; u32 kth = sh_kth;
      int shift = shifts[p], width = widths[p];
      u32 nb = 1u << width;
      int hs = shift + width;
      for (int i = tid; i < NPB; i += 256) {
        u64 key = kp[i];
        bool m = (p == 0) || ((key >> hs) == prefix);
        if (m) atomicAdd(&lh[(u32)(key >> shift) & (nb - 1u)], 1u);
      }
      __syncthreads();
      u32 l2[8]; u32 t2 = 0;
      for (int j = 0; j < 8; j++) {
        u32 b = (u32)(tid * 8 + j);
        u32 v = (b < nb) ? lh[b] : 0u;
        l2[j] = v; t2 += v;
      }
      sc[tid] = t2; __syncthreads();
      for (int off = 1; off < 256; off <<= 1) {
        u32 v = sc[tid]; u32 a = (tid >= off) ? sc[tid - off] : 0u;
        __syncthreads(); sc[tid] = v + a; __syncthreads();
      }
      u32 incl2 = sc[tid], excl2 = incl2 - t2;
      if (kth > excl2 && kth <= incl2) {
        u32 run = excl2;
        for (int j = 0; j < 8; j++) {
          run += l2[j];
          if (run >= kth) {
            u32 bin = (u32)(tid * 8 + j);
            u32 below = run - l2[j];
            u32 cnt = l2[j];
            u32 knew = kth - below;
            u64 pfull = (prefix << width) | (u64)bin;
            u32 M = (u32)PRE_N - knew + cnt;
            if (M <= SEL_CAP) {
              u64 lowmask = (shift > 0) ? ((1ULL << shift) - 1ULL) : 0ULL;
              sh_thresh = (pfull << shift) | lowmask;
              sh_state = 1;
            } else {
              sh_prefix = pfull; sh_kth = knew;
            }
            break;
          }
        }
      }
      __syncthreads();
    }
  }
  if (tid == 0) thresh_arr[img] = sh_thresh;
}

// Block-aggregated compaction + box decode for selected keys.
// Sort element: [desc:32 (bits 62..31) | anchoridx:18 (30..13) | slot:13 (12..0)].
// (desc,idx) are unique so slot never affects order; ~0 padding sorts last.
// The ~0.5% of threads holding a selected key do the 4 scattered bd loads here,
// hidden behind the block's sequential key sweep (960 blocks vs 16 before).
__global__ void k_compact(const u64* __restrict__ keys, const u64* __restrict__ thresh,
                          u32* __restrict__ selcnt, u64* __restrict__ sel,
                          const float* __restrict__ bd, const float* __restrict__ info,
                          float4* __restrict__ boxsel) {
  int img = blockIdx.y;
  int tid = threadIdx.x;
  u64 T = thresh[img];
  const u64* kp = keys + (size_t)img * NPB + (size_t)blockIdx.x * 3840;
  u32 mycnt = 0;
  #pragma unroll
  for (int j = 0; j < 15; j++) {
    u64 key = kp[j * 256 + tid];
    if (key <= T) mycnt++;
  }
  __shared__ u32 sc[256];
  __shared__ u32 sbase;
  sc[tid] = mycnt;
  __syncthreads();
  for (int off = 1; off < 256; off <<= 1) {
    u32 v = sc[tid];
    u32 add = (tid >= off) ? sc[tid - off] : 0u;
    __syncthreads();
    sc[tid] = v + add;
    __syncthreads();
  }
  if (tid == 255 && sc[255] > 0) sbase = atomicAdd(&selcnt[img], sc[255]);
  __syncthreads();
  if (mycnt == 0) return;
  u32 myoff = sbase + sc[tid] - mycnt;
  u64* sp = sel + (size_t)img * SEL_CAP;
  float4* bp = boxsel + (size_t)img * SEL_CAP;
  float imH = info[img*3+0], imW = info[img*3+1], ms = 16.0f * info[img*3+2];
  u32 c = 0;
  #pragma unroll
  for (int j = 0; j < 15; j++) {
    u64 key = kp[j * 256 + tid];
    if (key <= T) {
      u32 p = myoff + c;
      if (p < SEL_CAP) {
        u32 desc = (u32)(key >> 32);
        u32 idx = (u32)key;
        sp[p] = ((u64)desc << 31) | ((u64)idx << 13) | (u64)p;
        int a = (int)(idx % NA);
        int pos = (int)(idx / NA);
        float x1, y1, x2, y2; bool keep;
        box_from_deltas(bd, img, a, pos, imH, imW, ms, x1, y1, x2, y2, keep);
        bp[p] = make_float4(x1, y1, x2, y2);
      }
      c++;
    }
  }
}

// Stage 1: sort each 1024-key chunk ascending in LDS (8 chunks/image x 16 images
// = 128 blocks -> full-chip parallelism for the 55 bitonic phases).
__global__ void __launch_bounds__(256) k_sort1(u64* __restrict__ sel, const u32* __restrict__ selcnt) {
  __shared__ u64 s[1024];
  int img = blockIdx.y, c = blockIdx.x, tid = threadIdx.x;
  u32 cnt = selcnt[img]; if (cnt > SEL_CAP) cnt = SEL_CAP;
  u64* sp = sel + (size_t)img * SEL_CAP + (size_t)c * 1024;
  int gbase = c * 1024;
  for (int i = tid; i < 1024; i += 256) s[i] = ((u32)(gbase + i) < cnt) ? sp[i] : ~0ULL;
  __syncthreads();
  for (int k = 2; k <= 1024; k <<= 1) {
    for (int j = k >> 1; j > 0; j >>= 1) {
      for (int i = tid; i < 1024; i += 256) {
        int p = i ^ j;
        if (p > i) {
          u64 a = s[i], b = s[p];
          bool up = ((i & k) == 0);
          if (up ? (a > b) : (a < b)) { s[i] = b; s[p] = a; }
        }
      }
      __syncthreads();
    }
  }
  for (int i = tid; i < 1024; i += 256) sp[i] = s[i];
}

// Stage 2: merge 8 sorted 1024-runs -> 8192 via 3 merge-path levels (6 barriers).
// Epilogue: rank -> slot -> boxsel gather (128 KB/img, L2-resident; was 17 MB of
// scattered HBM in the fused version) + validity boundary.
__global__ void __launch_bounds__(1024) k_sort2(
    const u64* __restrict__ sel, const float4* __restrict__ boxsel,
    float4* __restrict__ boxes, u32* __restrict__ nvalid) {
  __shared__ u64 s[SEL_CAP];   // 64 KiB
  __shared__ int sh_nv;
  int img = blockIdx.x;
  int tid = threadIdx.x;
  const u64* sp = sel + (size_t)img * SEL_CAP;
  if (tid == 0) sh_nv = PRE_N;
  for (int i = tid; i < SEL_CAP; i += 1024) s[i] = sp[i];
  __syncthreads();
  int d0 = tid * 8;
  for (int L = 1024; L < SEL_CAP; L <<= 1) {
    int pairBase = d0 & ~(2 * L - 1);
    int d = d0 - pairBase;
    const u64* A = s + pairBase;
    const u64* B = s + pairBase + L;
    int lo = d - L; if (lo < 0) lo = 0;
    int hi = (d < L) ? d : L;
    while (lo < hi) {
      int mid = (lo + hi) >> 1;
      if (A[mid] <= B[d - 1 - mid]) lo = mid + 1; else hi = mid;
    }
    int ia = lo, ib = d - lo;
    u64 o[8];
    #pragma unroll
    for (int k = 0; k < 8; k++) {
      bool ta = (ib >= L) || (ia < L && A[ia] <= B[ib]);
      o[k] = ta ? A[ia++] : B[ib++];
    }
    __syncthreads();
    #pragma unroll
    for (int k = 0; k < 8; k++) s[d0 + k] = o[k];
    __syncthreads();
  }
  const float4* bp = boxsel + (size_t)img * SEL_CAP;
  for (int r = tid; r < PRE_N; r += 1024) {
    u64 key = s[r];
    u32 desc = (u32)(key >> 31);               // for padding ~0 this is 0xFFFFFFFF
    bool valid = desc < 0xFF800000u;           // score > -inf
    if (!valid) atomicMin(&sh_nv, r);
    float4 bx = valid ? bp[key & 0x1FFFu] : make_float4(0.f, 0.f, 0.f, 0.f);
    boxes[(size_t)img * PRE_N + r] = bx;
  }
  __syncthreads();
  if (tid == 0) nvalid[img] = (u32)sh_nv;
}

// NMS: batched-lazy greedy with (a) precomputed within-batch 64x64 suppression
// masks (serial chain = ffs + shfl + and), (b) conservative packed-u8 log-area
// gate on the kept-list scan (iou>0.7 => area ratio < 1/0.7), (c) exact
// divide-free compare (fmaf sign exact; IEEE divide only in the borderline
// band), (d) double-buffered candidate load overlapping the serial phase.
__global__ void __launch_bounds__(512) k_nms(const float4* __restrict__ boxes,
                                             const u32* __restrict__ nvalid_arr,
                                             float* __restrict__ out) {
  __shared__ float4 kbox[POST_N];
  __shared__ float karea[POST_N];
  __shared__ u64 kcodeW[(POST_N + 7) / 8];
  __shared__ float4 cb[2][64];
  __shared__ float car[2][64];
  __shared__ int cint[2][64];
  __shared__ u64 winm[2][64];
  __shared__ u64 supw[2][NMS_W];
  __shared__ int sh_nkept;
  int img = blockIdx.x;
  int tid = threadIdx.x;
  int lane = tid & 63;
  int wv = tid >> 6;
  int nvalid = (int)nvalid_arr[img];
  if (nvalid > PRE_N) nvalid = PRE_N;
  const float4* bb = boxes + (size_t)img * PRE_N;
  if (tid == 0) sh_nkept = 0;
  if (tid < 64) {
    float4 c = (tid < nvalid) ? bb[tid] : make_float4(0.f, 0.f, 0.f, 0.f);
    cb[0][tid] = c;
    float A = (c.z - c.x + 1.0f) * (c.w - c.y + 1.0f);
    car[0][tid] = A;
    cint[0][tid] = (int)rintf(8.0f * log2f(A));
  } else if (tid < 128) {
    winm[0][tid - 64] = 0;
  } else if (tid < 128 + NMS_W) {
    supw[0][tid - 128] = 0;
  }
  __syncthreads();
  int pb = 0;
  for (int base = 0; base < nvalid; base += 64, pb ^= 1) {
    int nk = sh_nkept;
    if (nk >= POST_N) break;
    int bn = nvalid - base; if (bn > 64) bn = 64;
    // ---- phase A: vs-kept tests + within-batch pair masks ----
    bool sup;
    u64 wpart = 0;
    {
      bool inb = lane < bn;
      sup = !inb;
      if (inb) {
        float4 C = cb[pb][lane];
        float A0 = car[pb][lane];
        int myc = cint[pb][lane];
        int nw = (nk + 7) >> 3;
        for (int jw = wv; jw < nw && !sup; jw += NMS_W) {
          u64 w = kcodeW[jw];
          int jbase = jw << 3;
          int jm = nk - jbase; if (jm > 8) jm = 8;
          for (int k = 0; k < jm; k++) {
            int d = (int)((w >> (k * 8)) & 0xFFu) - myc;
            if (d > 5 || d < -5) continue;          // conservative area-ratio gate
            int j = jbase + k;
            float4 K = kbox[j];
            float xx1 = fmaxf(K.x, C.x);
            float yy1 = fmaxf(K.y, C.y);
            float xx2 = fminf(K.z, C.z);
            float yy2 = fminf(K.w, C.w);
            float iw = fmaxf(0.0f, xx2 - xx1 + 1.0f);
            float ih = fmaxf(0.0f, yy2 - yy1 + 1.0f);
            float inter = iw * ih;
            float uni = (karea[j] + A0) - inter;    // reference operand order
            float ss = fmaf(0.7f, uni, -inter);
            bool sp;
            if (fabsf(ss) <= uni * 1e-6f) sp = (inter / uni > 0.7f);
            else sp = (ss < 0.0f);
            if (sp) { sup = true; break; }
          }
        }
        for (int j = lane + 1 + wv; j < bn; j += NMS_W) {
          float Aj = car[pb][j];
          if (Aj <= 0.6999f * A0 || A0 <= 0.6999f * Aj) continue;
          float4 J = cb[pb][j];
          float xx1 = fmaxf(C.x, J.x);
          float yy1 = fmaxf(C.y, J.y);
          float xx2 = fminf(C.z, J.z);
          float yy2 = fminf(C.w, J.w);
          float iw = fmaxf(0.0f, xx2 - xx1 + 1.0f);
          float ih = fmaxf(0.0f, yy2 - yy1 + 1.0f);
          float inter = iw * ih;
          float uni = (A0 + Aj) - inter;            // i (earlier) area first
          float ss = fmaf(0.7f, uni, -inter);
          bool sp;
          if (fabsf(ss) <= uni * 1e-6f) sp = (inter / uni > 0.7f);
          else sp = (ss < 0.0f);
          if (sp) wpart |= 1ULL << j;
        }
      }
    }
    u64 bm = __ballot(sup);
    if (lane == 0) supw[pb][wv] = bm;
    if (wpart) atomicOr(&winm[pb][lane], wpart);
    __syncthreads();
    // ---- phase B/C (wave 0) | prefetch next batch (waves 1-2) ----
    if (wv == 0) {
      u64 so = (lane < NMS_W) ? supw[pb][lane] : 0ULL;
      so |= __shfl_xor(so, 1);
      so |= __shfl_xor(so, 2);
      so |= __shfl_xor(so, 4);
      so = __shfl(so, 0);
      u64 validm = (bn >= 64) ? ~0ULL : ((1ULL << bn) - 1ULL);
      u64 wm = winm[pb][lane];
      u64 live = validm & ~so;
      u64 km = 0;
      int cnt = nk;
      while (live && cnt < POST_N) {
        int c = __ffsll((long long)live) - 1;
        km |= 1ULL << c;
        cnt++;
        u64 m = __shfl(wm, c);
        live &= ~m;
        live &= ~(1ULL << c);
      }
      if ((km >> lane) & 1ULL) {
        int rank = nk + __popcll(km & ((1ULL << lane) - 1ULL));
        float4 C = cb[pb][lane];
        kbox[rank] = C;
        karea[rank] = car[pb][lane];
        ((unsigned char*)kcodeW)[rank] = (unsigned char)cint[pb][lane];
        float* o = out + ((size_t)img * POST_N + rank) * 5;
        o[0] = (float)img; o[1] = C.x; o[2] = C.y; o[3] = C.z; o[4] = C.w;
      }
      if (lane == 0) sh_nkept = cnt;
    } else if (wv == 1) {
      int nb2 = base + 64;
      if (nb2 < nvalid) {
        int i = nb2 + lane;
        float4 c = (i < nvalid) ? bb[i] : make_float4(0.f, 0.f, 0.f, 0.f);
        cb[pb ^ 1][lane] = c;
        float A = (c.z - c.x + 1.0f) * (c.w - c.y + 1.0f);
        car[pb ^ 1][lane] = A;
        cint[pb ^ 1][lane] = (int)rintf(8.0f * log2f(A));
      }
    } else if (wv == 2) {
      winm[pb ^ 1][lane] = 0;
      if (lane < NMS_W) supw[pb ^ 1][lane] = 0;
    }
    __syncthreads();
  }
  int fk = sh_nkept;
  for (int r = fk + tid; r < POST_N; r += 512) {
    float* o = out + ((size_t)img * POST_N + r) * 5;
    o[0] = (float)img; o[1] = 0.f; o[2] = 0.f; o[3] = 0.f; o[4] = 0.f;
  }
}

extern "C" void kernel_launch(void* const* d_in, const int* in_sizes, int n_in,
                              void* d_out, int out_size, void* d_ws, size_t ws_size,
                              hipStream_t stream) {
  const float* sm   = (const float*)d_in[0];
  const float* bd   = (const float*)d_in[1];
  const float* info = (const float*)d_in[2];
  float* out = (float*)d_out;
  char* ws = (char*)d_ws;

  size_t off = 0;
  auto alloc = [&](size_t bytes) { size_t o = off; off += (bytes + 255) & ~(size_t)255; return o; };
  u64* keys     = (u64*)(ws + alloc((size_t)NBATCH * NPB * 8));        // ~29.5 MB
  size_t off_hist = alloc((size_t)NBATCH * UNI_BINS * 4);              // 128 KB
  u32* hist     = (u32*)(ws + off_hist);
  u32* selcnt   = (u32*)(ws + alloc(NBATCH * 4));                      // adjacent to hist
  size_t zero_end = off;
  u64* thresh   = (u64*)(ws + alloc(NBATCH * 8));
  u32* nvalid   = (u32*)(ws + alloc(NBATCH * 4));
  u64* sel      = (u64*)(ws + alloc((size_t)NBATCH * SEL_CAP * 8));    // 1 MB
  float4* boxsel= (float4*)(ws + alloc((size_t)NBATCH * SEL_CAP * 16));// 2 MB
  float4* boxes = (float4*)(ws + alloc((size_t)NBATCH * PRE_N * 16));  // 1.5 MB
  (void)ws_size; (void)in_sizes; (void)n_in; (void)out_size;

  hipMemsetAsync(ws + off_hist, 0, zero_end - off_hist, stream);       // hist + selcnt
  hipLaunchKernelGGL(k_scores_hist, dim3(960), dim3(256), 0, stream, sm, bd, info, keys, hist);
  hipLaunchKernelGGL(k_select, dim3(16), dim3(256), 0, stream, keys, hist, thresh);
  hipLaunchKernelGGL(k_compact, dim3(60, 16), dim3(256), 0, stream, keys, thresh, selcnt, sel, bd, info, boxsel);
  hipLaunchKernelGGL(k_sort1, dim3(8, 16), dim3(256), 0, stream, sel, selcnt);
  hipLaunchKernelGGL(k_sort2, dim3(16), dim3(1024), 0, stream, sel, boxsel, boxes, nvalid);
  hipLaunchKernelGGL(k_nms, dim3(16), dim3(512), 0, stream, boxes, nvalid, out);
}